// Round 6
// baseline (1175.012 us; speedup 1.0000x reference)
//
#include <hip/hip_runtime.h>

// Problem constants
#define NB    128
#define NC    256
#define NPOS  196
#define NHEAD 8
#define NAG   49
#define YSTR  150528      // 768*196 per-batch y floats
#define VOFF  50176       // v_raw offset inside y (256*196)
#define QOFF  100352      // q_raw offset inside y (512*196)
#define SCL   0.17677669529663687f   // 32^-0.5

// Workspace layout (floats). Total = 38,885,440 floats = 155.5 MB.
#define WS_Y    0u
#define WS_V5   19267584u
#define WS_AT   25690112u
#define WS_ATK  27295744u
#define WS_CHG  28901376u
#define WS_CMAP 28934144u
#define WS_PBT  28966912u
#define WS_AB   29043744u
#define WS_X1S  29120576u
#define WS_AGV  29153344u
#define WS_XO   30758976u
#define WS_WT   37181504u
#define WS_CWT  37247040u   // Wh: 1.6M ushort (fp16 conv5 weights, [tap][co][ci])

typedef __attribute__((ext_vector_type(8))) _Float16 half8;
typedef __attribute__((ext_vector_type(8))) short short8;
typedef __attribute__((ext_vector_type(4))) float f32x4;
typedef unsigned short ushort_t;
typedef unsigned int uint_t;

__device__ __forceinline__ float sigmoidf_(float x){ return 1.0f/(1.0f+__expf(-x)); }

__device__ __forceinline__ ushort_t f2h(float x){
  _Float16 h = (_Float16)x; return __builtin_bit_cast(ushort_t, h);
}
__device__ __forceinline__ float h2f(ushort_t u){
  return (float)__builtin_bit_cast(_Float16, u);
}

// bilinear upsample 7x7 -> 14x14 sample at (i,j), matching reference grid()
__device__ __forceinline__ float bilin7(const float* __restrict__ src, int i, int j){
  float pi = fmaxf(0.5f*(float)i - 0.25f, 0.f);
  int i0 = (int)pi; if (i0 > 6) i0 = 6;
  int i1 = i0 + 1;  if (i1 > 6) i1 = 6;
  float li = pi - (float)i0;
  float pj = fmaxf(0.5f*(float)j - 0.25f, 0.f);
  int j0 = (int)pj; if (j0 > 6) j0 = 6;
  int j1 = j0 + 1;  if (j1 > 6) j1 = 6;
  float lj = pj - (float)j0;
  float v00 = src[i0*7+j0], v01 = src[i0*7+j1];
  float v10 = src[i1*7+j0], v11 = src[i1*7+j1];
  float t0 = v00*(1.f-lj) + v01*lj;
  float t1 = v10*(1.f-lj) + v11*lj;
  return t0*(1.f-li) + t1*li;
}

// 5x5 conv over a zero-padded [18][20] plane, producing one 14-wide output row r.
__device__ __forceinline__ void conv5x5_row(const float* __restrict__ plane, int r,
                                            const float* __restrict__ w25, float* acc14){
  #pragma unroll
  for (int di = 0; di < 5; ++di){
    const float4* pr = (const float4*)(plane + (r+di)*20);
    float4 p0 = pr[0], p1 = pr[1], p2 = pr[2], p3 = pr[3], p4 = pr[4];
    float row[20] = {p0.x,p0.y,p0.z,p0.w, p1.x,p1.y,p1.z,p1.w, p2.x,p2.y,p2.z,p2.w,
                     p3.x,p3.y,p3.z,p3.w, p4.x,p4.y,p4.z,p4.w};
    #pragma unroll
    for (int dj = 0; dj < 5; ++dj){
      float w = w25[di*5+dj];
      #pragma unroll
      for (int j = 0; j < 14; ++j) acc14[j] = fmaf(row[j+dj], w, acc14[j]);
    }
  }
}

// ---------- prep kernels ----------
__global__ void k_pb(const float* __restrict__ an, const float* __restrict__ ah,
                     const float* __restrict__ aw, float* __restrict__ PBT){
  int t = blockIdx.x*256 + threadIdx.x;
  if (t >= NHEAD*NPOS*NAG) return;
  int a = t % NAG;
  int r = t / NAG;
  int n = r % NPOS;
  int h = r / NPOS;
  int i = n/14, j = n - (n/14)*14;
  float v = bilin7(an + ((size_t)h*NAG + a)*49, i, j);
  v += ah[((size_t)h*NAG + a)*14 + i] + aw[((size_t)h*NAG + a)*14 + j];
  PBT[t] = v;   // [h][n][a]
}

__global__ void k_ab(const float* __restrict__ na, const float* __restrict__ ha,
                     const float* __restrict__ wa, float* __restrict__ AB){
  int t = blockIdx.x*256 + threadIdx.x;
  if (t >= NHEAD*NPOS*NAG) return;
  int a = t % NAG;
  int r = t / NAG;
  int n = r % NPOS;
  int h = r / NPOS;
  int i = n/14, j = n - (n/14)*14;
  float v = bilin7(na + ((size_t)h*NAG + a)*49, i, j);
  v += ha[((size_t)h*14 + i)*NAG + a] + wa[((size_t)h*14 + j)*NAG + a];
  AB[t] = v;    // [h][n][a]
}

__global__ void k_wt(const float* __restrict__ pw, float* __restrict__ WT){
  int t = blockIdx.x*256 + threadIdx.x;
  if (t >= 65536) return;
  int k = t >> 8, c = t & 255;
  WT[t] = pw[c*256 + k];          // WT[k][c] = proj_w[c][k]
}

// conv5 weights -> fp16, layout [tap][co][ci]
__global__ void k_cw2(const float* __restrict__ cw, ushort_t* __restrict__ Wh){
  int t = blockIdx.x*256 + threadIdx.x;
  if (t >= 1638400) return;
  int ci = t & 255;
  int r  = t >> 8;
  int co = r & 255;
  int tap = r >> 8;
  Wh[t] = f2h(cw[((size_t)co*256 + ci)*25 + tap]);
}

// ---------- lka depthwise-ish conv (groups=256, 3 outputs per input channel) ----------
__global__ __launch_bounds__(256) void k_lka(const float* __restrict__ x, const float* __restrict__ lw,
                                             const float* __restrict__ lb, float* __restrict__ Y){
  int b = blockIdx.x >> 3, gb = blockIdx.x & 7;
  int g0 = gb*32;                               // input channels [g0,g0+32)
  __shared__ __align__(16) float pl[32*360];    // [ch][18*20] padded planes
  int tid = threadIdx.x;
  for (int t = tid; t < 32*360; t += 256) pl[t] = 0.f;
  __syncthreads();
  for (int t = tid; t < 32*196; t += 256){
    int gl = t & 31, s = t >> 5;
    int i = s/14, j = s - i*14;
    pl[gl*360 + (i+2)*20 + j + 2] = x[((size_t)b*196 + s)*256 + g0 + gl];
  }
  __syncthreads();
  for (int t = tid; t < 96*14; t += 256){
    int ocl = t/14, r = t - ocl*14;
    int o  = g0*3 + ocl;          // output channel; uses input channel o/3
    int gl = ocl/3;
    float w25[25];
    #pragma unroll
    for (int u = 0; u < 25; ++u) w25[u] = lw[o*25 + u];
    float acc[14];
    float bv = lb[o];
    #pragma unroll
    for (int j = 0; j < 14; ++j) acc[j] = bv;
    conv5x5_row(&pl[gl*360], r, w25, acc);
    float* dst = Y + ((size_t)b*768 + o)*196 + r*14;
    #pragma unroll
    for (int j = 0; j < 14; ++j) dst[j] = acc[j];
  }
}

// ---------- conv5 via fp16 MFMA implicit GEMM ----------
__global__ __launch_bounds__(256, 2) void k_conv5(const float* __restrict__ Y,
    const ushort_t* __restrict__ Wh, const float* __restrict__ cb, float* __restrict__ V5){
  int b = blockIdx.x >> 2, cog = blockIdx.x & 3;
  int co0 = cog*64;
  __shared__ __align__(16) ushort_t Pt[360*40];     // fp16 A: [pos][ci32 swizzled]
  __shared__ __align__(16) ushort_t Wsm[5*64*40];   // fp16 B: [tap-of-row][co][ci32 swizzled]
  __shared__ float T[32*200];                       // epilogue transpose
  int tid  = threadIdx.x;
  int lane = tid & 63, wv = tid >> 6;
  int mrow = lane & 15, quad = lane >> 4;

  // zero-fill Pt once; borders stay zero across chunks
  for (int t = tid; t < 7200; t += 256) ((uint_t*)Pt)[t] = 0;

  // per-lane A plane-row base per m-tile (unpadded base; taps add di*20+dj)
  int prow[4];
  #pragma unroll
  for (int mt = 0; mt < 4; ++mt){
    int s = wv*64 + mt*16 + mrow;
    int p0 = 0;
    if (s < 196){ int i = s/14, j = s - i*14; p0 = i*20 + j; }
    prow[mt] = p0;
  }

  f32x4 acc[4][4];
  #pragma unroll
  for (int mt = 0; mt < 4; ++mt)
    #pragma unroll
    for (int nt = 0; nt < 4; ++nt) acc[mt][nt] = (f32x4){0.f,0.f,0.f,0.f};

  const float* src = Y + (size_t)b*YSTR + VOFF;   // v_raw [ci][s]
  int wco = tid >> 2, wpart = tid & 3;            // W-staging roles

  #pragma unroll 1
  for (int cc = 0; cc < 8; ++cc){
    __syncthreads();
    // stage A: 32 ci planes -> fp16 swizzled [pos][ci]
    if (tid < 196){
      int s = tid; int i = s/14, j = s - i*14;
      int p = (i+2)*20 + (j+2);
      const float* s0 = src + (cc*32)*196 + s;
      #pragma unroll
      for (int cp = 0; cp < 16; ++cp){
        float v0 = s0[(2*cp)*196];
        float v1 = s0[(2*cp+1)*196];
        uint_t pk = (uint_t)f2h(v0) | ((uint_t)f2h(v1) << 16);
        int q = cp >> 2;
        *(uint_t*)&Pt[p*40 + (((q ^ p) & 3) << 3) + ((2*cp) & 7)] = pk;
      }
    }
    #pragma unroll 1
    for (int di = 0; di < 5; ++di){
      __syncthreads();      // Wsm free to overwrite; also fences A writes (di=0)
      // stage W: taps di*5..di*5+4, 64 co x 32 ci fp16 each
      #pragma unroll
      for (int tp = 0; tp < 5; ++tp){
        int tap = di*5 + tp;
        const short8 g = *(const short8*)(Wh + ((size_t)tap*256 + co0 + wco)*256 + cc*32 + wpart*8);
        *(short8*)&Wsm[(tp*64 + wco)*40 + (((wpart ^ wco) & 3) << 3)] = g;
      }
      __syncthreads();
      #pragma unroll
      for (int dj = 0; dj < 5; ++dj){
        half8 a[4], bb[4];
        #pragma unroll
        for (int nt = 0; nt < 4; ++nt){
          int co = nt*16 + mrow;
          bb[nt] = *(const half8*)&Wsm[(dj*64 + co)*40 + (((quad ^ co) & 3) << 3)];
        }
        #pragma unroll
        for (int mt = 0; mt < 4; ++mt){
          int p = prow[mt] + di*20 + dj;
          a[mt] = *(const half8*)&Pt[p*40 + (((quad ^ p) & 3) << 3)];
        }
        #pragma unroll
        for (int mt = 0; mt < 4; ++mt)
          #pragma unroll
          for (int nt = 0; nt < 4; ++nt)
            acc[mt][nt] = __builtin_amdgcn_mfma_f32_16x16x32_f16(a[mt], bb[nt], acc[mt][nt], 0, 0, 0);
      }
    }
  }

  // epilogue: transpose through LDS, then stores into scrambled v5
  #pragma unroll
  for (int hf = 0; hf < 2; ++hf){
    __syncthreads();
    #pragma unroll
    for (int ntl = 0; ntl < 2; ++ntl){
      int nt = hf*2 + ntl;
      int col = ntl*16 + mrow;            // co local within half (0..31)
      #pragma unroll
      for (int mt = 0; mt < 4; ++mt){
        int sbase = wv*64 + mt*16 + quad*4;
        #pragma unroll
        for (int r = 0; r < 4; ++r){
          int s = sbase + r;
          if (s < 196) T[col*200 + s] = acc[mt][nt][r];
        }
      }
    }
    __syncthreads();
    for (int t = tid; t < 6272; t += 256){
      int cl = t / 196;                   // co local 0..31
      int f = (co0 + hf*32)*196 + t;
      float val = T[t + cl*4] + cb[co0 + hf*32 + cl];
      V5[(size_t)b*50176 + (size_t)(f & 255)*196 + (f >> 8)] = val;
    }
  }
}

// ---------- agent token pooling: at = 2x2-mean of q_raw, atk = 2x2-max of k_raw ----------
__global__ __launch_bounds__(256) void k_pool(const float* __restrict__ Y, float* __restrict__ AT, float* __restrict__ ATK){
  int b = blockIdx.x; int c = threadIdx.x;
  const float* qp = Y + ((size_t)b*768 + 512 + c)*196;
  const float* kp = Y + ((size_t)b*768 + c)*196;
  for (int a = 0; a < 49; ++a){
    int p1 = a/7, p2 = a - p1*7;
    int s = p1*28 + p2*2;
    float q0 = qp[s], q1 = qp[s+1], q2 = qp[s+14], q3 = qp[s+15];
    AT[((size_t)b*49 + a)*256 + c] = 0.25f*(q0+q1+q2+q3);
    float k0 = kp[s], k1 = kp[s+1], k2 = kp[s+14], k3 = kp[s+15];
    ATK[((size_t)b*49 + a)*256 + c] = fmaxf(fmaxf(k0,k1), fmaxf(k2,k3));
  }
}

// ---------- cbam stage A: channel gate ----------
__global__ __launch_bounds__(256) void k_cbam_a(const float* __restrict__ V5,
    const float* __restrict__ caa1w, const float* __restrict__ caa1b,
    const float* __restrict__ caa2w, const float* __restrict__ caa2b,
    const float* __restrict__ cam1w, const float* __restrict__ cam1b,
    const float* __restrict__ cam2w, const float* __restrict__ cam2b,
    float* __restrict__ CHG){
  int b = blockIdx.x, c = threadIdx.x;
  __shared__ float avg[256], mx[256], t1[16], t2[16];
  const float* pp = V5 + ((size_t)b*256 + c)*196;
  float s = 0.f, m = -1e30f;
  for (int i = 0; i < 196; ++i){ float v = pp[i]; s += v; m = fmaxf(m, v); }
  avg[c] = s * (1.0f/196.0f); mx[c] = m;
  __syncthreads();
  if (c < 16){
    float a1 = caa1b[c], a2 = cam1b[c];
    #pragma unroll 4
    for (int k = 0; k < 256; ++k){
      a1 = fmaf(caa1w[(c*256 + k)*9 + 4], avg[k], a1);   // 3x3 center tap
      a2 = fmaf(cam1w[c*256 + k], mx[k], a2);            // 1x1
    }
    t1[c] = fmaxf(a1, 0.f);
    t2[c] = fmaxf(a2, 0.f);
  }
  __syncthreads();
  float y1 = caa2b[c], y2 = cam2b[c];
  #pragma unroll
  for (int k = 0; k < 16; ++k){
    y1 = fmaf(caa2w[(c*16 + k)*9 + 4], t1[k], y1);
    y2 = fmaf(cam2w[c*16 + k], t2[k], y2);
  }
  CHG[b*256 + c] = sigmoidf_(sigmoidf_(y1) + sigmoidf_(y2));
}

// ---------- cbam stage B: spatial mask (9x9 pad4 over [mean,max]) + in-place gate ----------
__global__ __launch_bounds__(256) void k_cbam_b(float* __restrict__ V5, const float* __restrict__ CHG,
    const float* __restrict__ saw, const float* __restrict__ sab){
  int b = blockIdx.x; int tid = threadIdx.x;
  __shared__ float chg[256];
  __shared__ float mp[22*22], xp[22*22];
  __shared__ float mk[196];
  chg[tid] = CHG[b*256 + tid];
  for (int t = tid; t < 484; t += 256){ mp[t] = 0.f; xp[t] = 0.f; }
  __syncthreads();
  if (tid < 196){
    int i = tid/14, j = tid - i*14;
    float s = 0.f, m = -1e30f;
    const float* vb = V5 + (size_t)b*256*196 + tid;
    for (int c = 0; c < 256; ++c){
      float v = chg[c] * vb[c*196];
      s += v; m = fmaxf(m, v);
    }
    mp[(i+4)*22 + j+4] = s*(1.f/256.f);
    xp[(i+4)*22 + j+4] = m;
  }
  __syncthreads();
  if (tid < 196){
    int i = tid/14, j = tid - i*14;
    float acc = sab[0];
    for (int di = 0; di < 9; ++di){
      #pragma unroll
      for (int dj = 0; dj < 9; ++dj){
        acc = fmaf(mp[(i+di)*22 + j+dj], saw[di*9+dj], acc);
        acc = fmaf(xp[(i+di)*22 + j+dj], saw[81 + di*9+dj], acc);
      }
    }
    mk[tid] = sigmoidf_(acc);
  }
  __syncthreads();
  if (tid < 196){
    float m = mk[tid];
    float* vb = V5 + (size_t)b*256*196 + tid;
    for (int c = 0; c < 256; ++c) vb[c*196] = chg[c]*vb[c*196]*m;
  }
}

// ---------- big NxN attention; only the per-(b,c) mean of x1 is needed downstream ----------
__global__ __launch_bounds__(256) void k_attn(const float* __restrict__ Y, const float* __restrict__ rpbt,
                                              float* __restrict__ X1S){
  int b = blockIdx.x >> 3, h = blockIdx.x & 7;
  __shared__ float rp[729];
  __shared__ float xs[196*33];
  int tid = threadIdx.x;
  for (int t = tid; t < 729; t += 256) rp[t] = rpbt[t*8 + h];
  __syncthreads();
  const float* yb = Y + (size_t)b*YSTR;
  if (tid < 196){
    int n = tid;
    float q[32];
    {
      const float4* q4 = (const float4*)(yb + QOFF + (size_t)n*256 + h*32);
      #pragma unroll
      for (int u = 0; u < 8; ++u){
        float4 v = q4[u];
        q[4*u] = v.x*SCL; q[4*u+1] = v.y*SCL; q[4*u+2] = v.z*SCL; q[4*u+3] = v.w*SCL;
      }
    }
    int ri = n/14, ci = n - ri*14;
    int bidx = (ri + 13)*27 + (ci + 13);
    float acc[32];
    #pragma unroll
    for (int d = 0; d < 32; ++d) acc[d] = 0.f;
    float l = 0.f;
    int rj = 0, cj = 0;
    for (int j = 0; j < 196; ++j){
      const float4* k4 = (const float4*)(yb + (size_t)j*256 + h*32);
      float s0 = 0.f, s1 = 0.f;
      #pragma unroll
      for (int u = 0; u < 8; u += 2){
        float4 a = k4[u], bb = k4[u+1];
        s0 = fmaf(q[4*u+0],a.x, fmaf(q[4*u+1],a.y, fmaf(q[4*u+2],a.z, fmaf(q[4*u+3],a.w, s0))));
        s1 = fmaf(q[4*u+4],bb.x, fmaf(q[4*u+5],bb.y, fmaf(q[4*u+6],bb.z, fmaf(q[4*u+7],bb.w, s1))));
      }
      float s = s0 + s1 + rp[bidx - rj*27 - cj];
      float p = __expf(s);       // logits are O(0.1): max-free softmax is safe
      l += p;
      const float4* v4 = (const float4*)(yb + VOFF + (size_t)j*256 + h*32);
      #pragma unroll
      for (int u = 0; u < 8; ++u){
        float4 vv = v4[u];
        acc[4*u]   = fmaf(p, vv.x, acc[4*u]);
        acc[4*u+1] = fmaf(p, vv.y, acc[4*u+1]);
        acc[4*u+2] = fmaf(p, vv.z, acc[4*u+2]);
        acc[4*u+3] = fmaf(p, vv.w, acc[4*u+3]);
      }
      if (++cj == 14){ cj = 0; ++rj; }
    }
    float inv = 1.f/l;
    #pragma unroll
    for (int d = 0; d < 32; ++d) xs[n*33 + d] = acc[d]*inv;
  }
  __syncthreads();
  if (tid < 32){
    float s = 0.f;
    for (int n = 0; n < 196; ++n) s += xs[n*33 + tid];
    X1S[(size_t)b*256 + h*32 + tid] = s*(1.f/196.f);   // mean over n of x1[b,:,c]
  }
}

// ---------- chan_inter on x1 mean -> sigmoid gate CMAP ----------
__global__ __launch_bounds__(256) void k_cinter(const float* __restrict__ X1S,
    const float* __restrict__ ci1w, const float* __restrict__ ci1b,
    const float* __restrict__ bng, const float* __restrict__ bnb,
    const float* __restrict__ ci2w, const float* __restrict__ ci2b, float* __restrict__ CMAP){
  int b = blockIdx.x, c = threadIdx.x;
  __shared__ float p[256], tt[16];
  p[c] = X1S[b*256 + c];
  __syncthreads();
  if (c < 16){
    float a = ci1b[c];
    #pragma unroll 4
    for (int k = 0; k < 256; ++k) a = fmaf(ci1w[(c*256+k)*25 + 12], p[k], a);  // 5x5 center
    const float invs = 0.9999950000375f;   // 1/sqrt(1+1e-5)
    tt[c] = fmaxf(fmaf(bng[c]*invs, a, bnb[c]), 0.f);
  }
  __syncthreads();
  float a = ci2b[c];
  #pragma unroll
  for (int k = 0; k < 16; ++k) a = fmaf(ci2w[(c*16+k)*25 + 12], tt[k], a);
  CMAP[b*256 + c] = sigmoidf_(a);
}

// ---------- agent_v: 512 threads; halved serial loops + unroll-2 PV ----------
// agent_v = softmax(at*scale@K^T+pb)@V1 + softmax(atk*scale@Q^T+pb)@V.
// Logits: 8 waves stride n by 8 (25 iters). PV: wave = (n-half, d-octet),
// 98 iters unrolled by 2 (paired loads). fp16 S and partial-output buffers.
__global__ __launch_bounds__(512, 6) void k_agentv(const float* __restrict__ Y, const float* __restrict__ V5,
    const float* __restrict__ AT, const float* __restrict__ ATK,
    const float* __restrict__ PBT, float* __restrict__ AGV){
  int b = blockIdx.x >> 3, h = blockIdx.x & 7;
  __shared__ ushort_t S0[196*49];     // exp(agent_attn logits) fp16, [n][a]
  __shared__ ushort_t S1[196*49];     // exp(agent_attn1 logits)
  __shared__ float2 part[8*64];       // per-wave (sum0, sum1) per agent
  __shared__ ushort_t Pacc[2*49*32];  // merged partial outputs [nhalf][a][d]
  int tid = threadIdx.x;
  int wv = tid >> 6, lane = tid & 63;
  const float* yb = Y + (size_t)b*YSTR;
  float ar[32], akr[32];
  if (lane < 49){
    const float4* ap = (const float4*)(AT  + ((size_t)b*49 + lane)*256 + h*32);
    const float4* kp = (const float4*)(ATK + ((size_t)b*49 + lane)*256 + h*32);
    #pragma unroll
    for (int u = 0; u < 8; ++u){
      float4 a = ap[u], k = kp[u];
      ar[4*u]=a.x; ar[4*u+1]=a.y; ar[4*u+2]=a.z; ar[4*u+3]=a.w;
      akr[4*u]=k.x; akr[4*u+1]=k.y; akr[4*u+2]=k.z; akr[4*u+3]=k.w;
    }
  }
  // ---- merged logits: s0 = (ar.K[n])*SCL + pb ; s1 = (akr.Q[n])*SCL^2 + pb ----
  float l0 = 0.f, l1 = 0.f;
  if (lane < 49){
    for (int n = wv; n < 196; n += 8){
      const float4* k4 = (const float4*)(yb + (size_t)n*256 + h*32);
      const float4* q4 = (const float4*)(yb + QOFF + (size_t)n*256 + h*32);
      float s0 = 0.f, s1 = 0.f;
      #pragma unroll
      for (int u = 0; u < 8; ++u){
        float4 kv = k4[u], qv = q4[u];
        s0 = fmaf(ar[4*u],kv.x, fmaf(ar[4*u+1],kv.y, fmaf(ar[4*u+2],kv.z, fmaf(ar[4*u+3],kv.w, s0))));
        s1 = fmaf(akr[4*u],qv.x, fmaf(akr[4*u+1],qv.y, fmaf(akr[4*u+2],qv.z, fmaf(akr[4*u+3],qv.w, s1))));
      }
      float pb = PBT[((size_t)h*196 + n)*49 + lane];
      ushort_t e0 = f2h(__expf(fmaf(s0, SCL, pb)));
      ushort_t e1 = f2h(__expf(fmaf(s1, 0.03125f, pb)));
      S0[n*49 + lane] = e0;
      S1[n*49 + lane] = e1;
      l0 += h2f(e0);               // sum the quantized values for consistency
      l1 += h2f(e1);
    }
  }
  part[wv*64 + lane] = make_float2(l0, l1);
  __syncthreads();
  // ---- PV: wave = (n-half, d-octet); 98 iters, unroll 2 ----
  int nh = wv >> 2, d0 = (wv & 3)*8;
  if (lane < 49){
    float s0t = 0.f, s1t = 0.f;
    #pragma unroll
    for (int w = 0; w < 8; ++w){
      float2 p = part[w*64 + lane];
      s0t += p.x; s1t += p.y;
    }
    float inv0 = 1.f/s0t, inv1 = 1.f/s1t;
    int n0 = nh*98;
    float acc0[8], acc1[8];
    #pragma unroll
    for (int d = 0; d < 8; ++d){ acc0[d] = 0.f; acc1[d] = 0.f; }
    const float* v0p = V5 + (size_t)b*50176 + (h*32 + d0)*196 + n0;   // [r][196]
    const float* v1p = yb + VOFF + (size_t)n0*256 + h*32 + d0;        // [n][8]
    #pragma unroll 1
    for (int nn = 0; nn < 98; nn += 2){
      int n = n0 + nn;
      float pa0 = h2f(S0[n*49 + lane]);
      float pb0 = h2f(S0[(n+1)*49 + lane]);
      float pa1 = h2f(S1[n*49 + lane]);
      float pb1 = h2f(S1[(n+1)*49 + lane]);
      #pragma unroll
      for (int r = 0; r < 8; ++r){
        float2 v2 = *(const float2*)(v0p + r*196 + nn);   // paired dwordx2
        acc0[r] = fmaf(pa0, v2.x, fmaf(pb0, v2.y, acc0[r]));
      }
      const float4* va = (const float4*)(v1p + (size_t)nn*256);
      const float4* vb = (const float4*)(v1p + (size_t)(nn+1)*256);
      float4 a0 = va[0], a1 = va[1], b0 = vb[0], b1 = vb[1];
      acc1[0] = fmaf(pa1, a0.x, fmaf(pb1, b0.x, acc1[0]));
      acc1[1] = fmaf(pa1, a0.y, fmaf(pb1, b0.y, acc1[1]));
      acc1[2] = fmaf(pa1, a0.z, fmaf(pb1, b0.z, acc1[2]));
      acc1[3] = fmaf(pa1, a0.w, fmaf(pb1, b0.w, acc1[3]));
      acc1[4] = fmaf(pa1, a1.x, fmaf(pb1, b1.x, acc1[4]));
      acc1[5] = fmaf(pa1, a1.y, fmaf(pb1, b1.y, acc1[5]));
      acc1[6] = fmaf(pa1, a1.z, fmaf(pb1, b1.z, acc1[6]));
      acc1[7] = fmaf(pa1, a1.w, fmaf(pb1, b1.w, acc1[7]));
    }
    #pragma unroll
    for (int d = 0; d < 8; ++d)
      Pacc[(nh*49 + lane)*32 + d0 + d] = f2h(acc0[d]*inv0 + acc1[d]*inv1);
  }
  __syncthreads();
  if (wv < 4 && lane < 49){
    int db = wv*8;
    float* dst = AGV + (((size_t)(b*8 + h)*49) + lane)*32 + db;
    #pragma unroll
    for (int d = 0; d < 8; ++d)
      dst[d] = h2f(Pacc[lane*32 + db + d]) + h2f(Pacc[(49 + lane)*32 + db + d]);
  }
}

// ---------- xo1 = (softmax(q*scale@at^T+ab) + softmax(k*scale@atk^T+ab)) @ agent_v ----------
__global__ __launch_bounds__(256) void k_xo1(const float* __restrict__ Y,
    const float* __restrict__ AT, const float* __restrict__ ATK,
    const float* __restrict__ AB, const float* __restrict__ AGV, float* __restrict__ XO){
  int b = blockIdx.x >> 3, h = blockIdx.x & 7;
  __shared__ float P[98*53];
  __shared__ float sAGV[49*32];
  int tid = threadIdx.x;
  int wv = tid >> 6, lane = tid & 63;
  const float* yb = Y + (size_t)b*YSTR;
  float ar[32], akr[32];
  if (lane < 49){
    const float4* ap = (const float4*)(AT  + ((size_t)b*49 + lane)*256 + h*32);
    const float4* kp = (const float4*)(ATK + ((size_t)b*49 + lane)*256 + h*32);
    #pragma unroll
    for (int u = 0; u < 8; ++u){
      float4 a = ap[u], k = kp[u];
      ar[4*u]=a.x; ar[4*u+1]=a.y; ar[4*u+2]=a.z; ar[4*u+3]=a.w;
      akr[4*u]=k.x; akr[4*u+1]=k.y; akr[4*u+2]=k.z; akr[4*u+3]=k.w;
    }
  }
  {
    const float* agvb = AGV + (size_t)(b*8 + h)*49*32;
    for (int t = tid; t < 1568; t += 256) sAGV[t] = agvb[t];
  }
  #pragma unroll 1
  for (int chunk = 0; chunk < 2; ++chunk){
    __syncthreads();    // P safe to overwrite; (chunk 0: also fences sAGV stores)
    for (int i = wv; i < 98; i += 4){
      int n = chunk*98 + i;
      float eq = 0.f, ek = 0.f;
      if (lane < 49){
        float ab = AB[((size_t)h*196 + n)*49 + lane];
        const float4* q4 = (const float4*)(yb + QOFF + (size_t)n*256 + h*32);
        const float4* k4 = (const float4*)(yb + (size_t)n*256 + h*32);
        float sq = 0.f, sk = 0.f;
        #pragma unroll
        for (int u = 0; u < 8; ++u){
          float4 qv = q4[u], kv = k4[u];
          sq = fmaf(ar[4*u],qv.x, fmaf(ar[4*u+1],qv.y, fmaf(ar[4*u+2],qv.z, fmaf(ar[4*u+3],qv.w, sq))));
          sk = fmaf(akr[4*u],kv.x, fmaf(akr[4*u+1],kv.y, fmaf(akr[4*u+2],kv.z, fmaf(akr[4*u+3],kv.w, sk))));
        }
        eq = __expf(fmaf(sq, 0.03125f, ab));   // (q*scale . at*scale)
        ek = __expf(fmaf(sk, SCL, ab));        // (k*scale . atk)
      }
      float tq = eq, tk = ek;
      #pragma unroll
      for (int o = 32; o > 0; o >>= 1){ tq += __shfl_xor(tq, o); tk += __shfl_xor(tk, o); }
      if (lane < 49) P[i*53 + lane] = eq/tq + ek/tk;
    }
    __syncthreads();
    if (tid < 196){
      int i = tid >> 1, dh = tid & 1;      // row i, d half
      int n = chunk*98 + i;
      float out[16];
      #pragma unroll
      for (int d = 0; d < 16; ++d) out[d] = 0.f;
      const float* pr = &P[i*53];
      #pragma unroll 7
      for (int a = 0; a < 49; ++a){
        float pv = pr[a];
        const float4* g4 = (const float4*)&sAGV[a*32 + dh*16];
        #pragma unroll
        for (int u = 0; u < 4; ++u){
          float4 gv = g4[u];
          out[4*u]   = fmaf(pv, gv.x, out[4*u]);
          out[4*u+1] = fmaf(pv, gv.y, out[4*u+1]);
          out[4*u+2] = fmaf(pv, gv.z, out[4*u+2]);
          out[4*u+3] = fmaf(pv, gv.w, out[4*u+3]);
        }
      }
      float* dst = XO + ((size_t)b*196 + n)*256 + h*32 + dh*16;
      #pragma unroll
      for (int d = 0; d < 16; ++d) dst[d] = out[d];
    }
  }
}

// ---------- fused depthwise conv: dwc(conv_x2 + qc), bias 2*dwc_b, accumulated into XO ----------
__global__ __launch_bounds__(256) void k_dwc(const float* __restrict__ Y, const float* __restrict__ CMAP,
    const float* __restrict__ dw, const float* __restrict__ db, float* __restrict__ XO){
  int b = blockIdx.x >> 3, cg = blockIdx.x & 7;
  int c0 = cg*32;
  __shared__ __align__(16) float pl[32*360];
  int tid = threadIdx.x;
  for (int t = tid; t < 32*360; t += 256) pl[t] = 0.f;
  __syncthreads();
  const float* yq = Y + (size_t)b*YSTR + QOFF;
  for (int t = tid; t < 32*196; t += 256){
    int cl = t & 31, s = t >> 5;
    int c = c0 + cl;
    int G = s*256 + c;                 // head-major flat index for conv_x2's scramble
    int hh = G / 6272;
    int rem = G - hh*6272;
    int n = rem >> 5, d = rem & 31;
    float cx2 = CMAP[b*256 + c] * yq[n*256 + hh*32 + d];   // sigmoid(cmap)*qs
    float qc  = yq[G];                                     // qc collapses to identity gather
    float v = SCL*(cx2 + qc);
    int i = s/14, j = s - i*14;
    pl[cl*360 + (i+2)*20 + j + 2] = v;
  }
  __syncthreads();
  for (int t = tid; t < 32*14; t += 256){
    int cl = t/14, r = t - cl*14;
    int c = c0 + cl;
    float w25[25];
    #pragma unroll
    for (int u = 0; u < 25; ++u) w25[u] = dw[c*25 + u];
    float acc[14];
    float b2 = 2.f*db[c];
    #pragma unroll
    for (int j = 0; j < 14; ++j) acc[j] = b2;
    conv5x5_row(&pl[cl*360], r, w25, acc);
    float* dst = XO + ((size_t)b*196 + r*14)*256 + c;
    #pragma unroll
    for (int j = 0; j < 14; ++j) dst[j*256] += acc[j];
  }
}

// ---------- final projection: out = XO @ proj_w^T + proj_b ----------
__global__ __launch_bounds__(256) void k_proj(const float* __restrict__ XO, const float* __restrict__ WT,
    const float* __restrict__ pbias, float* __restrict__ OUT){
  int bb = blockIdx.x / 7, nt = blockIdx.x % 7;
  int n0 = nt*28;
  int c = threadIdx.x;
  const float* xb = XO + ((size_t)bb*196 + n0)*256;
  float acc[28];
  #pragma unroll
  for (int r = 0; r < 28; ++r) acc[r] = 0.f;
  for (int k = 0; k < 256; k += 4){
    float w0 = WT[(k+0)*256 + c];
    float w1 = WT[(k+1)*256 + c];
    float w2 = WT[(k+2)*256 + c];
    float w3 = WT[(k+3)*256 + c];
    #pragma unroll
    for (int r = 0; r < 28; ++r){
      float4 xv = *(const float4*)(xb + r*256 + k);   // uniform address -> scalar/L1 path
      acc[r] = fmaf(xv.x, w0, fmaf(xv.y, w1, fmaf(xv.z, w2, fmaf(xv.w, w3, acc[r]))));
    }
  }
  float bv = pbias[c];
  float* dst = OUT + ((size_t)bb*196 + n0)*256 + c;
  #pragma unroll
  for (int r = 0; r < 28; ++r) dst[r*256] = acc[r] + bv;
}

extern "C" void kernel_launch(void* const* d_in, const int* in_sizes, int n_in,
                              void* d_out, int out_size, void* d_ws, size_t ws_size,
                              hipStream_t stream){
  (void)in_sizes; (void)n_in; (void)out_size; (void)ws_size;
  const float* x       = (const float*)d_in[0];
  const float* lka_w   = (const float*)d_in[3];
  const float* lka_b   = (const float*)d_in[4];
  const float* conv5_w = (const float*)d_in[5];
  const float* conv5_b = (const float*)d_in[6];
  const float* caa1_w  = (const float*)d_in[7];
  const float* caa1_b  = (const float*)d_in[8];
  const float* caa2_w  = (const float*)d_in[9];
  const float* caa2_b  = (const float*)d_in[10];
  const float* cam1_w  = (const float*)d_in[11];
  const float* cam1_b  = (const float*)d_in[12];
  const float* cam2_w  = (const float*)d_in[13];
  const float* cam2_b  = (const float*)d_in[14];
  const float* sa_w    = (const float*)d_in[15];
  const float* sa_b    = (const float*)d_in[16];
  const float* ci1_w   = (const float*)d_in[17];
  const float* ci1_b   = (const float*)d_in[18];
  const float* bn_g    = (const float*)d_in[19];
  const float* bn_b    = (const float*)d_in[20];
  const float* ci2_w   = (const float*)d_in[21];
  const float* ci2_b   = (const float*)d_in[22];
  const float* rpbt    = (const float*)d_in[23];
  const float* an_bias = (const float*)d_in[24];
  const float* na_bias = (const float*)d_in[25];
  const float* ah_bias = (const float*)d_in[26];
  const float* aw_bias = (const float*)d_in[27];
  const float* ha_bias = (const float*)d_in[28];
  const float* wa_bias = (const float*)d_in[29];
  const float* dwc_w   = (const float*)d_in[30];
  const float* dwc_b   = (const float*)d_in[31];
  const float* proj_w  = (const float*)d_in[32];
  const float* proj_b  = (const float*)d_in[33];
  float* out = (float*)d_out;
  float* ws = (float*)d_ws;

  float* Y    = ws + WS_Y;
  float* V5   = ws + WS_V5;
  float* AT   = ws + WS_AT;
  float* ATK  = ws + WS_ATK;
  float* CHG  = ws + WS_CHG;
  float* CMAP = ws + WS_CMAP;
  float* PBT  = ws + WS_PBT;
  float* AB   = ws + WS_AB;
  float* X1S  = ws + WS_X1S;
  float* AGV  = ws + WS_AGV;
  float* XO   = ws + WS_XO;
  float* WT   = ws + WS_WT;
  ushort_t* Wh = (ushort_t*)(ws + WS_CWT);

  k_pb   <<<301, 256, 0, stream>>>(an_bias, ah_bias, aw_bias, PBT);
  k_ab   <<<301, 256, 0, stream>>>(na_bias, ha_bias, wa_bias, AB);
  k_wt   <<<256, 256, 0, stream>>>(proj_w, WT);
  k_cw2  <<<6400, 256, 0, stream>>>(conv5_w, Wh);
  k_lka  <<<1024, 256, 0, stream>>>(x, lka_w, lka_b, Y);
  k_conv5<<<512, 256, 0, stream>>>(Y, Wh, conv5_b, V5);
  k_pool <<<128, 256, 0, stream>>>(Y, AT, ATK);
  k_cbam_a<<<128, 256, 0, stream>>>(V5, caa1_w, caa1_b, caa2_w, caa2_b,
                                    cam1_w, cam1_b, cam2_w, cam2_b, CHG);
  k_cbam_b<<<128, 256, 0, stream>>>(V5, CHG, sa_w, sa_b);
  k_attn <<<1024, 256, 0, stream>>>(Y, rpbt, X1S);
  k_cinter<<<128, 256, 0, stream>>>(X1S, ci1_w, ci1_b, bn_g, bn_b, ci2_w, ci2_b, CMAP);
  k_agentv<<<1024, 512, 0, stream>>>(Y, V5, AT, ATK, PBT, AGV);
  k_xo1  <<<1024, 256, 0, stream>>>(Y, AT, ATK, AB, AGV, XO);
  k_dwc  <<<1024, 256, 0, stream>>>(Y, CMAP, dwc_w, dwc_b, XO);
  k_proj <<<896, 256, 0, stream>>>(XO, WT, proj_b, out);
}

// Round 7
// 930.964 us; speedup vs baseline: 1.2621x; 1.2621x over previous
//
#include <hip/hip_runtime.h>

// Problem constants
#define NB    128
#define NC    256
#define NPOS  196
#define NHEAD 8
#define NAG   49
#define YSTR  150528      // 768*196 per-batch y floats
#define VOFF  50176       // v_raw offset inside y (256*196)
#define QOFF  100352      // q_raw offset inside y (512*196)
#define SCL   0.17677669529663687f   // 32^-0.5

// Workspace layout (floats). Total = 38,885,440 floats = 155.5 MB.
#define WS_Y    0u
#define WS_V5   19267584u
#define WS_AT   25690112u
#define WS_ATK  27295744u
#define WS_CHG  28901376u
#define WS_CMAP 28934144u
#define WS_PBT  28966912u
#define WS_AB   29043744u
#define WS_X1S  29120576u
#define WS_AGV  29153344u
#define WS_XO   30758976u
#define WS_WT   37181504u
#define WS_CWT  37247040u   // Wh: 1.6M ushort (fp16 conv5 weights, [tap][co][ci])

typedef __attribute__((ext_vector_type(8))) _Float16 half8;
typedef __attribute__((ext_vector_type(8))) short short8;
typedef __attribute__((ext_vector_type(4))) short short4v;
typedef __attribute__((ext_vector_type(4))) float f32x4;
typedef unsigned short ushort_t;
typedef unsigned int uint_t;

__device__ __forceinline__ float sigmoidf_(float x){ return 1.0f/(1.0f+__expf(-x)); }

__device__ __forceinline__ ushort_t f2h(float x){
  _Float16 h = (_Float16)x; return __builtin_bit_cast(ushort_t, h);
}
__device__ __forceinline__ float h2f(ushort_t u){
  return (float)__builtin_bit_cast(_Float16, u);
}

// bilinear upsample 7x7 -> 14x14 sample at (i,j), matching reference grid()
__device__ __forceinline__ float bilin7(const float* __restrict__ src, int i, int j){
  float pi = fmaxf(0.5f*(float)i - 0.25f, 0.f);
  int i0 = (int)pi; if (i0 > 6) i0 = 6;
  int i1 = i0 + 1;  if (i1 > 6) i1 = 6;
  float li = pi - (float)i0;
  float pj = fmaxf(0.5f*(float)j - 0.25f, 0.f);
  int j0 = (int)pj; if (j0 > 6) j0 = 6;
  int j1 = j0 + 1;  if (j1 > 6) j1 = 6;
  float lj = pj - (float)j0;
  float v00 = src[i0*7+j0], v01 = src[i0*7+j1];
  float v10 = src[i1*7+j0], v11 = src[i1*7+j1];
  float t0 = v00*(1.f-lj) + v01*lj;
  float t1 = v10*(1.f-lj) + v11*lj;
  return t0*(1.f-li) + t1*li;
}

// 5x5 conv over a zero-padded [18][20] plane, producing one 14-wide output row r.
__device__ __forceinline__ void conv5x5_row(const float* __restrict__ plane, int r,
                                            const float* __restrict__ w25, float* acc14){
  #pragma unroll
  for (int di = 0; di < 5; ++di){
    const float4* pr = (const float4*)(plane + (r+di)*20);
    float4 p0 = pr[0], p1 = pr[1], p2 = pr[2], p3 = pr[3], p4 = pr[4];
    float row[20] = {p0.x,p0.y,p0.z,p0.w, p1.x,p1.y,p1.z,p1.w, p2.x,p2.y,p2.z,p2.w,
                     p3.x,p3.y,p3.z,p3.w, p4.x,p4.y,p4.z,p4.w};
    #pragma unroll
    for (int dj = 0; dj < 5; ++dj){
      float w = w25[di*5+dj];
      #pragma unroll
      for (int j = 0; j < 14; ++j) acc14[j] = fmaf(row[j+dj], w, acc14[j]);
    }
  }
}

// ---------- prep kernels ----------
__global__ void k_pb(const float* __restrict__ an, const float* __restrict__ ah,
                     const float* __restrict__ aw, float* __restrict__ PBT){
  int t = blockIdx.x*256 + threadIdx.x;
  if (t >= NHEAD*NPOS*NAG) return;
  int a = t % NAG;
  int r = t / NAG;
  int n = r % NPOS;
  int h = r / NPOS;
  int i = n/14, j = n - (n/14)*14;
  float v = bilin7(an + ((size_t)h*NAG + a)*49, i, j);
  v += ah[((size_t)h*NAG + a)*14 + i] + aw[((size_t)h*NAG + a)*14 + j];
  PBT[t] = v;   // [h][n][a]
}

__global__ void k_ab(const float* __restrict__ na, const float* __restrict__ ha,
                     const float* __restrict__ wa, float* __restrict__ AB){
  int t = blockIdx.x*256 + threadIdx.x;
  if (t >= NHEAD*NPOS*NAG) return;
  int a = t % NAG;
  int r = t / NAG;
  int n = r % NPOS;
  int h = r / NPOS;
  int i = n/14, j = n - (n/14)*14;
  float v = bilin7(na + ((size_t)h*NAG + a)*49, i, j);
  v += ha[((size_t)h*14 + i)*NAG + a] + wa[((size_t)h*14 + j)*NAG + a];
  AB[t] = v;    // [h][n][a]
}

__global__ void k_wt(const float* __restrict__ pw, float* __restrict__ WT){
  int t = blockIdx.x*256 + threadIdx.x;
  if (t >= 65536) return;
  int k = t >> 8, c = t & 255;
  WT[t] = pw[c*256 + k];          // WT[k][c] = proj_w[c][k]
}

// conv5 weights -> fp16, layout [tap][co][ci]
__global__ void k_cw2(const float* __restrict__ cw, ushort_t* __restrict__ Wh){
  int t = blockIdx.x*256 + threadIdx.x;
  if (t >= 1638400) return;
  int ci = t & 255;
  int r  = t >> 8;
  int co = r & 255;
  int tap = r >> 8;
  Wh[t] = f2h(cw[((size_t)co*256 + ci)*25 + tap]);
}

// ---------- lka depthwise-ish conv (groups=256, 3 outputs per input channel) ----------
__global__ __launch_bounds__(256) void k_lka(const float* __restrict__ x, const float* __restrict__ lw,
                                             const float* __restrict__ lb, float* __restrict__ Y){
  int b = blockIdx.x >> 3, gb = blockIdx.x & 7;
  int g0 = gb*32;                               // input channels [g0,g0+32)
  __shared__ __align__(16) float pl[32*360];    // [ch][18*20] padded planes
  int tid = threadIdx.x;
  for (int t = tid; t < 32*360; t += 256) pl[t] = 0.f;
  __syncthreads();
  for (int t = tid; t < 32*196; t += 256){
    int gl = t & 31, s = t >> 5;
    int i = s/14, j = s - i*14;
    pl[gl*360 + (i+2)*20 + j + 2] = x[((size_t)b*196 + s)*256 + g0 + gl];
  }
  __syncthreads();
  for (int t = tid; t < 96*14; t += 256){
    int ocl = t/14, r = t - ocl*14;
    int o  = g0*3 + ocl;          // output channel; uses input channel o/3
    int gl = ocl/3;
    float w25[25];
    #pragma unroll
    for (int u = 0; u < 25; ++u) w25[u] = lw[o*25 + u];
    float acc[14];
    float bv = lb[o];
    #pragma unroll
    for (int j = 0; j < 14; ++j) acc[j] = bv;
    conv5x5_row(&pl[gl*360], r, w25, acc);
    float* dst = Y + ((size_t)b*768 + o)*196 + r*14;
    #pragma unroll
    for (int j = 0; j < 14; ++j) dst[j] = acc[j];
  }
}

// ---------- conv5 via fp16 MFMA implicit GEMM ----------
__global__ __launch_bounds__(256, 2) void k_conv5(const float* __restrict__ Y,
    const ushort_t* __restrict__ Wh, const float* __restrict__ cb, float* __restrict__ V5){
  int b = blockIdx.x >> 2, cog = blockIdx.x & 3;
  int co0 = cog*64;
  __shared__ __align__(16) ushort_t Pt[360*40];     // fp16 A: [pos][ci32 swizzled]
  __shared__ __align__(16) ushort_t Wsm[5*64*40];   // fp16 B: [tap-of-row][co][ci32 swizzled]
  __shared__ float T[32*200];                       // epilogue transpose
  int tid  = threadIdx.x;
  int lane = tid & 63, wv = tid >> 6;
  int mrow = lane & 15, quad = lane >> 4;

  // zero-fill Pt once; borders stay zero across chunks
  for (int t = tid; t < 7200; t += 256) ((uint_t*)Pt)[t] = 0;

  // per-lane A plane-row base per m-tile (unpadded base; taps add di*20+dj)
  int prow[4];
  #pragma unroll
  for (int mt = 0; mt < 4; ++mt){
    int s = wv*64 + mt*16 + mrow;
    int p0 = 0;
    if (s < 196){ int i = s/14, j = s - i*14; p0 = i*20 + j; }
    prow[mt] = p0;
  }

  f32x4 acc[4][4];
  #pragma unroll
  for (int mt = 0; mt < 4; ++mt)
    #pragma unroll
    for (int nt = 0; nt < 4; ++nt) acc[mt][nt] = (f32x4){0.f,0.f,0.f,0.f};

  const float* src = Y + (size_t)b*YSTR + VOFF;   // v_raw [ci][s]
  int wco = tid >> 2, wpart = tid & 3;            // W-staging roles

  #pragma unroll 1
  for (int cc = 0; cc < 8; ++cc){
    __syncthreads();
    // stage A: 32 ci planes -> fp16 swizzled [pos][ci]
    if (tid < 196){
      int s = tid; int i = s/14, j = s - i*14;
      int p = (i+2)*20 + (j+2);
      const float* s0 = src + (cc*32)*196 + s;
      #pragma unroll
      for (int cp = 0; cp < 16; ++cp){
        float v0 = s0[(2*cp)*196];
        float v1 = s0[(2*cp+1)*196];
        uint_t pk = (uint_t)f2h(v0) | ((uint_t)f2h(v1) << 16);
        int q = cp >> 2;
        *(uint_t*)&Pt[p*40 + (((q ^ p) & 3) << 3) + ((2*cp) & 7)] = pk;
      }
    }
    #pragma unroll 1
    for (int di = 0; di < 5; ++di){
      __syncthreads();      // Wsm free to overwrite; also fences A writes (di=0)
      // stage W: taps di*5..di*5+4, 64 co x 32 ci fp16 each
      #pragma unroll
      for (int tp = 0; tp < 5; ++tp){
        int tap = di*5 + tp;
        const short8 g = *(const short8*)(Wh + ((size_t)tap*256 + co0 + wco)*256 + cc*32 + wpart*8);
        *(short8*)&Wsm[(tp*64 + wco)*40 + (((wpart ^ wco) & 3) << 3)] = g;
      }
      __syncthreads();
      #pragma unroll
      for (int dj = 0; dj < 5; ++dj){
        half8 a[4], bb[4];
        #pragma unroll
        for (int nt = 0; nt < 4; ++nt){
          int co = nt*16 + mrow;
          bb[nt] = *(const half8*)&Wsm[(dj*64 + co)*40 + (((quad ^ co) & 3) << 3)];
        }
        #pragma unroll
        for (int mt = 0; mt < 4; ++mt){
          int p = prow[mt] + di*20 + dj;
          a[mt] = *(const half8*)&Pt[p*40 + (((quad ^ p) & 3) << 3)];
        }
        #pragma unroll
        for (int mt = 0; mt < 4; ++mt)
          #pragma unroll
          for (int nt = 0; nt < 4; ++nt)
            acc[mt][nt] = __builtin_amdgcn_mfma_f32_16x16x32_f16(a[mt], bb[nt], acc[mt][nt], 0, 0, 0);
      }
    }
  }

  // epilogue: transpose through LDS, then stores into scrambled v5
  #pragma unroll
  for (int hf = 0; hf < 2; ++hf){
    __syncthreads();
    #pragma unroll
    for (int ntl = 0; ntl < 2; ++ntl){
      int nt = hf*2 + ntl;
      int col = ntl*16 + mrow;            // co local within half (0..31)
      #pragma unroll
      for (int mt = 0; mt < 4; ++mt){
        int sbase = wv*64 + mt*16 + quad*4;
        #pragma unroll
        for (int r = 0; r < 4; ++r){
          int s = sbase + r;
          if (s < 196) T[col*200 + s] = acc[mt][nt][r];
        }
      }
    }
    __syncthreads();
    for (int t = tid; t < 6272; t += 256){
      int cl = t / 196;                   // co local 0..31
      int f = (co0 + hf*32)*196 + t;
      float val = T[t + cl*4] + cb[co0 + hf*32 + cl];
      V5[(size_t)b*50176 + (size_t)(f & 255)*196 + (f >> 8)] = val;
    }
  }
}

// ---------- agent token pooling: at = 2x2-mean of q_raw, atk = 2x2-max of k_raw ----------
__global__ __launch_bounds__(256) void k_pool(const float* __restrict__ Y, float* __restrict__ AT, float* __restrict__ ATK){
  int b = blockIdx.x; int c = threadIdx.x;
  const float* qp = Y + ((size_t)b*768 + 512 + c)*196;
  const float* kp = Y + ((size_t)b*768 + c)*196;
  for (int a = 0; a < 49; ++a){
    int p1 = a/7, p2 = a - p1*7;
    int s = p1*28 + p2*2;
    float q0 = qp[s], q1 = qp[s+1], q2 = qp[s+14], q3 = qp[s+15];
    AT[((size_t)b*49 + a)*256 + c] = 0.25f*(q0+q1+q2+q3);
    float k0 = kp[s], k1 = kp[s+1], k2 = kp[s+14], k3 = kp[s+15];
    ATK[((size_t)b*49 + a)*256 + c] = fmaxf(fmaxf(k0,k1), fmaxf(k2,k3));
  }
}

// ---------- cbam stage A: channel gate ----------
__global__ __launch_bounds__(256) void k_cbam_a(const float* __restrict__ V5,
    const float* __restrict__ caa1w, const float* __restrict__ caa1b,
    const float* __restrict__ caa2w, const float* __restrict__ caa2b,
    const float* __restrict__ cam1w, const float* __restrict__ cam1b,
    const float* __restrict__ cam2w, const float* __restrict__ cam2b,
    float* __restrict__ CHG){
  int b = blockIdx.x, c = threadIdx.x;
  __shared__ float avg[256], mx[256], t1[16], t2[16];
  const float* pp = V5 + ((size_t)b*256 + c)*196;
  float s = 0.f, m = -1e30f;
  for (int i = 0; i < 196; ++i){ float v = pp[i]; s += v; m = fmaxf(m, v); }
  avg[c] = s * (1.0f/196.0f); mx[c] = m;
  __syncthreads();
  if (c < 16){
    float a1 = caa1b[c], a2 = cam1b[c];
    #pragma unroll 4
    for (int k = 0; k < 256; ++k){
      a1 = fmaf(caa1w[(c*256 + k)*9 + 4], avg[k], a1);   // 3x3 center tap
      a2 = fmaf(cam1w[c*256 + k], mx[k], a2);            // 1x1
    }
    t1[c] = fmaxf(a1, 0.f);
    t2[c] = fmaxf(a2, 0.f);
  }
  __syncthreads();
  float y1 = caa2b[c], y2 = cam2b[c];
  #pragma unroll
  for (int k = 0; k < 16; ++k){
    y1 = fmaf(caa2w[(c*16 + k)*9 + 4], t1[k], y1);
    y2 = fmaf(cam2w[c*16 + k], t2[k], y2);
  }
  CHG[b*256 + c] = sigmoidf_(sigmoidf_(y1) + sigmoidf_(y2));
}

// ---------- cbam stage B: spatial mask (9x9 pad4 over [mean,max]) + in-place gate ----------
__global__ __launch_bounds__(256) void k_cbam_b(float* __restrict__ V5, const float* __restrict__ CHG,
    const float* __restrict__ saw, const float* __restrict__ sab){
  int b = blockIdx.x; int tid = threadIdx.x;
  __shared__ float chg[256];
  __shared__ float mp[22*22], xp[22*22];
  __shared__ float mk[196];
  chg[tid] = CHG[b*256 + tid];
  for (int t = tid; t < 484; t += 256){ mp[t] = 0.f; xp[t] = 0.f; }
  __syncthreads();
  if (tid < 196){
    int i = tid/14, j = tid - i*14;
    float s = 0.f, m = -1e30f;
    const float* vb = V5 + (size_t)b*256*196 + tid;
    for (int c = 0; c < 256; ++c){
      float v = chg[c] * vb[c*196];
      s += v; m = fmaxf(m, v);
    }
    mp[(i+4)*22 + j+4] = s*(1.f/256.f);
    xp[(i+4)*22 + j+4] = m;
  }
  __syncthreads();
  if (tid < 196){
    int i = tid/14, j = tid - i*14;
    float acc = sab[0];
    for (int di = 0; di < 9; ++di){
      #pragma unroll
      for (int dj = 0; dj < 9; ++dj){
        acc = fmaf(mp[(i+di)*22 + j+dj], saw[di*9+dj], acc);
        acc = fmaf(xp[(i+di)*22 + j+dj], saw[81 + di*9+dj], acc);
      }
    }
    mk[tid] = sigmoidf_(acc);
  }
  __syncthreads();
  if (tid < 196){
    float m = mk[tid];
    float* vb = V5 + (size_t)b*256*196 + tid;
    for (int c = 0; c < 256; ++c) vb[c*196] = chg[c]*vb[c*196]*m;
  }
}

// ---------- big NxN attention; only the per-(b,c) mean of x1 is needed downstream ----------
__global__ __launch_bounds__(256) void k_attn(const float* __restrict__ Y, const float* __restrict__ rpbt,
                                              float* __restrict__ X1S){
  int b = blockIdx.x >> 3, h = blockIdx.x & 7;
  __shared__ float rp[729];
  __shared__ float xs[196*33];
  int tid = threadIdx.x;
  for (int t = tid; t < 729; t += 256) rp[t] = rpbt[t*8 + h];
  __syncthreads();
  const float* yb = Y + (size_t)b*YSTR;
  if (tid < 196){
    int n = tid;
    float q[32];
    {
      const float4* q4 = (const float4*)(yb + QOFF + (size_t)n*256 + h*32);
      #pragma unroll
      for (int u = 0; u < 8; ++u){
        float4 v = q4[u];
        q[4*u] = v.x*SCL; q[4*u+1] = v.y*SCL; q[4*u+2] = v.z*SCL; q[4*u+3] = v.w*SCL;
      }
    }
    int ri = n/14, ci = n - ri*14;
    int bidx = (ri + 13)*27 + (ci + 13);
    float acc[32];
    #pragma unroll
    for (int d = 0; d < 32; ++d) acc[d] = 0.f;
    float l = 0.f;
    int rj = 0, cj = 0;
    for (int j = 0; j < 196; ++j){
      const float4* k4 = (const float4*)(yb + (size_t)j*256 + h*32);
      float s0 = 0.f, s1 = 0.f;
      #pragma unroll
      for (int u = 0; u < 8; u += 2){
        float4 a = k4[u], bb = k4[u+1];
        s0 = fmaf(q[4*u+0],a.x, fmaf(q[4*u+1],a.y, fmaf(q[4*u+2],a.z, fmaf(q[4*u+3],a.w, s0))));
        s1 = fmaf(q[4*u+4],bb.x, fmaf(q[4*u+5],bb.y, fmaf(q[4*u+6],bb.z, fmaf(q[4*u+7],bb.w, s1))));
      }
      float s = s0 + s1 + rp[bidx - rj*27 - cj];
      float p = __expf(s);       // logits are O(0.1): max-free softmax is safe
      l += p;
      const float4* v4 = (const float4*)(yb + VOFF + (size_t)j*256 + h*32);
      #pragma unroll
      for (int u = 0; u < 8; ++u){
        float4 vv = v4[u];
        acc[4*u]   = fmaf(p, vv.x, acc[4*u]);
        acc[4*u+1] = fmaf(p, vv.y, acc[4*u+1]);
        acc[4*u+2] = fmaf(p, vv.z, acc[4*u+2]);
        acc[4*u+3] = fmaf(p, vv.w, acc[4*u+3]);
      }
      if (++cj == 14){ cj = 0; ++rj; }
    }
    float inv = 1.f/l;
    #pragma unroll
    for (int d = 0; d < 32; ++d) xs[n*33 + d] = acc[d]*inv;
  }
  __syncthreads();
  if (tid < 32){
    float s = 0.f;
    for (int n = 0; n < 196; ++n) s += xs[n*33 + tid];
    X1S[(size_t)b*256 + h*32 + tid] = s*(1.f/196.f);   // mean over n of x1[b,:,c]
  }
}

// ---------- chan_inter on x1 mean -> sigmoid gate CMAP ----------
__global__ __launch_bounds__(256) void k_cinter(const float* __restrict__ X1S,
    const float* __restrict__ ci1w, const float* __restrict__ ci1b,
    const float* __restrict__ bng, const float* __restrict__ bnb,
    const float* __restrict__ ci2w, const float* __restrict__ ci2b, float* __restrict__ CMAP){
  int b = blockIdx.x, c = threadIdx.x;
  __shared__ float p[256], tt[16];
  p[c] = X1S[b*256 + c];
  __syncthreads();
  if (c < 16){
    float a = ci1b[c];
    #pragma unroll 4
    for (int k = 0; k < 256; ++k) a = fmaf(ci1w[(c*256+k)*25 + 12], p[k], a);  // 5x5 center
    const float invs = 0.9999950000375f;   // 1/sqrt(1+1e-5)
    tt[c] = fmaxf(fmaf(bng[c]*invs, a, bnb[c]), 0.f);
  }
  __syncthreads();
  float a = ci2b[c];
  #pragma unroll
  for (int k = 0; k < 16; ++k) a = fmaf(ci2w[(c*16+k)*25 + 12], tt[k], a);
  CMAP[b*256 + c] = sigmoidf_(a);
}

// ---------- agent_v via fp16 MFMA ----------
// Per (b,h): S0[196][49] = (K . AT^T), S1 = (Q . ATK^T) as 16x16x32 MFMAs (K=32
// exactly); exp(+pb) applied on C-frags, stored transposed ST[a][n] fp16;
// PV out[49][32] = ST . V as 7-step K-loop MFMAs. Same operand patterns as
// k_conv5 (verified): operands [row][k] fp16, b128 frag reads; C col=N,row=M.
__global__ __launch_bounds__(256) void k_agentv(const float* __restrict__ Y, const float* __restrict__ V5,
    const float* __restrict__ AT, const float* __restrict__ ATK,
    const float* __restrict__ PBT, float* __restrict__ AGV){
  int b = blockIdx.x >> 3, h = blockIdx.x & 7;
  __shared__ __align__(16) ushort_t ST[64*232];   // exp-scores, [a][n pad 232]
  __shared__ __align__(16) ushort_t R[8704];      // staging region (17408 B)
  __shared__ float psum[4*64];
  __shared__ float inv0s[64], inv1s[64];
  int tid = threadIdx.x, wv = tid >> 6, lane = tid & 63;
  int mrow = lane & 15, quad = lane >> 4;
  const float* yb = Y + (size_t)b*YSTR;
  ushort_t* Kh = R;            // [208][32] fp16 rows (K or Q)
  ushort_t* Ah = R + 6656;     // [64][32] fp16 rows (AT or ATK)
  ushort_t* Vt = R;            // [32][232] fp16 rows (V1 or V)
  f32x4 out0[2], out1[2];

  // ---- one-time zero fills: ST cols 208..223 (cols 224-231 never read) ----
  for (int t = tid; t < 512; t += 256){      // 64 rows x 16 cols /2 per uint
    int a = t >> 3, c2 = 208 + ((t & 7) << 1);
    *(uint_t*)&ST[a*232 + c2] = 0;
  }

  #pragma unroll 1
  for (int pass = 0; pass < 2; ++pass){
    // ---- stage rows (K|Q into Kh; AT|ATK into Ah), zero pads ----
    for (int t = tid; t < 192; t += 256) ((uint_t*)Kh)[3136 + t] = 0;   // rows 196-207
    for (int t = tid; t < 240; t += 256) ((uint_t*)Ah)[784 + t] = 0;    // rows 49-63
    {
      const float* rsrc = yb + (pass ? QOFF : 0) + h*32;
      for (int t = tid; t < 3136; t += 256){
        int n = t >> 4, dp = (t & 15) << 1;
        const float2 v = *(const float2*)(rsrc + (size_t)n*256 + dp);
        ((uint_t*)Kh)[n*16 + (dp >> 1)] = (uint_t)f2h(v.x) | ((uint_t)f2h(v.y) << 16);
      }
      const float* asrc = (pass ? ATK : AT) + (size_t)b*49*256 + h*32;
      for (int t = tid; t < 784; t += 256){
        int a = t >> 4, dp = (t & 15) << 1;
        const float2 v = *(const float2*)(asrc + (size_t)a*256 + dp);
        ((uint_t*)Ah)[a*16 + (dp >> 1)] = (uint_t)f2h(v.x) | ((uint_t)f2h(v.y) << 16);
      }
    }
    __syncthreads();
    // ---- logits: ntile = wv; 13 mtiles; exp(+pb) -> ST[a][n] ----
    {
      float lscl = pass ? 0.03125f : SCL;
      int ag = wv*16 + mrow;                 // agent (C col)
      half8 bfr = *(const half8*)&Ah[ag*32 + quad*8];
      #pragma unroll 1
      for (int mt = 0; mt < 13; ++mt){
        half8 afr = *(const half8*)&Kh[(mt*16 + mrow)*32 + quad*8];
        f32x4 c = (f32x4){0.f,0.f,0.f,0.f};
        c = __builtin_amdgcn_mfma_f32_16x16x32_f16(afr, bfr, c, 0, 0, 0);
        int n0 = mt*16 + quad*4;
        short4v pk;
        #pragma unroll
        for (int r = 0; r < 4; ++r){
          int n = n0 + r;
          float pb = PBT[((size_t)h*196 + n)*49 + ag];   // n>=196 lands in AB (in-ws, masked)
          float e = (n < 196) ? __expf(fmaf(c[r], lscl, pb)) : 0.f;
          pk[r] = (short)f2h(e);
        }
        *(short4v*)&ST[ag*232 + n0] = pk;
      }
    }
    __syncthreads();
    // ---- denominators + stage V ----
    {
      int a = tid >> 2, q = tid & 3;
      float s = 0.f;
      #pragma unroll
      for (int u = 0; u < 7; ++u){
        short8 v8 = *(const short8*)&ST[a*232 + q*56 + u*8];
        #pragma unroll
        for (int e = 0; e < 8; ++e) s += h2f((ushort_t)v8[e]);
      }
      psum[q*64 + a] = s;
    }
    if (pass == 0){
      const float* vsrc = V5 + (size_t)b*50176 + h*32*196;   // [d][196]
      for (int t = tid; t < 3136; t += 256){
        int d = t / 98, np = t - (t/98)*98;
        const float2 v = *(const float2*)(vsrc + (size_t)d*196 + 2*np);
        *(uint_t*)&Vt[d*232 + 2*np] = (uint_t)f2h(v.x) | ((uint_t)f2h(v.y) << 16);
      }
    } else {
      const float* vsrc = yb + VOFF + h*32;                  // [n][256]
      for (int t = tid; t < 3136; t += 256){
        int d = t / 98, np = t - (t/98)*98;
        float v0 = vsrc[(size_t)(2*np)*256 + d];
        float v1 = vsrc[(size_t)(2*np+1)*256 + d];
        *(uint_t*)&Vt[d*232 + 2*np] = (uint_t)f2h(v0) | ((uint_t)f2h(v1) << 16);
      }
    }
    for (int t = tid; t < 448; t += 256){    // zero V cols 196..223
      int d = t / 14, c2 = 196 + 2*(t - (t/14)*14);
      *(uint_t*)&Vt[d*232 + c2] = 0;
    }
    __syncthreads();
    // ---- PV: mtile = wv (a rows); ntile 0..1 (d cols); 7 k-steps ----
    {
      f32x4* outp = pass ? out1 : out0;
      #pragma unroll
      for (int nt = 0; nt < 2; ++nt){
        f32x4 c = (f32x4){0.f,0.f,0.f,0.f};
        #pragma unroll
        for (int ks = 0; ks < 7; ++ks){
          half8 afr = *(const half8*)&ST[(wv*16 + mrow)*232 + ks*32 + quad*8];
          half8 bfr = *(const half8*)&Vt[(nt*16 + mrow)*232 + ks*32 + quad*8];
          c = __builtin_amdgcn_mfma_f32_16x16x32_f16(afr, bfr, c, 0, 0, 0);
        }
        outp[nt] = c;
      }
      if (tid < 64){
        float s = psum[tid] + psum[64+tid] + psum[128+tid] + psum[192+tid];
        float* invp = pass ? inv1s : inv0s;
        invp[tid] = 1.f / s;
      }
    }
    __syncthreads();   // ST/Vt free for next pass; inv visible
  }
  // ---- epilogue: combine + scatter ----
  #pragma unroll
  for (int nt = 0; nt < 2; ++nt){
    int d = nt*16 + mrow;
    #pragma unroll
    for (int r = 0; r < 4; ++r){
      int a = wv*16 + quad*4 + r;
      if (a < 49)
        AGV[(((size_t)(b*8 + h)*49) + a)*32 + d] = out0[nt][r]*inv0s[a] + out1[nt][r]*inv1s[a];
    }
  }
}

// ---------- xo1 = (softmax(q*scale@at^T+ab) + softmax(k*scale@atk^T+ab)) @ agent_v ----------
__global__ __launch_bounds__(256) void k_xo1(const float* __restrict__ Y,
    const float* __restrict__ AT, const float* __restrict__ ATK,
    const float* __restrict__ AB, const float* __restrict__ AGV, float* __restrict__ XO){
  int b = blockIdx.x >> 3, h = blockIdx.x & 7;
  __shared__ float P[98*53];
  __shared__ float sAGV[49*32];
  int tid = threadIdx.x;
  int wv = tid >> 6, lane = tid & 63;
  const float* yb = Y + (size_t)b*YSTR;
  float ar[32], akr[32];
  if (lane < 49){
    const float4* ap = (const float4*)(AT  + ((size_t)b*49 + lane)*256 + h*32);
    const float4* kp = (const float4*)(ATK + ((size_t)b*49 + lane)*256 + h*32);
    #pragma unroll
    for (int u = 0; u < 8; ++u){
      float4 a = ap[u], k = kp[u];
      ar[4*u]=a.x; ar[4*u+1]=a.y; ar[4*u+2]=a.z; ar[4*u+3]=a.w;
      akr[4*u]=k.x; akr[4*u+1]=k.y; akr[4*u+2]=k.z; akr[4*u+3]=k.w;
    }
  }
  {
    const float* agvb = AGV + (size_t)(b*8 + h)*49*32;
    for (int t = tid; t < 1568; t += 256) sAGV[t] = agvb[t];
  }
  #pragma unroll 1
  for (int chunk = 0; chunk < 2; ++chunk){
    __syncthreads();    // P safe to overwrite; (chunk 0: also fences sAGV stores)
    for (int i = wv; i < 98; i += 4){
      int n = chunk*98 + i;
      float eq = 0.f, ek = 0.f;
      if (lane < 49){
        float ab = AB[((size_t)h*196 + n)*49 + lane];
        const float4* q4 = (const float4*)(yb + QOFF + (size_t)n*256 + h*32);
        const float4* k4 = (const float4*)(yb + (size_t)n*256 + h*32);
        float sq = 0.f, sk = 0.f;
        #pragma unroll
        for (int u = 0; u < 8; ++u){
          float4 qv = q4[u], kv = k4[u];
          sq = fmaf(ar[4*u],qv.x, fmaf(ar[4*u+1],qv.y, fmaf(ar[4*u+2],qv.z, fmaf(ar[4*u+3],qv.w, sq))));
          sk = fmaf(akr[4*u],kv.x, fmaf(akr[4*u+1],kv.y, fmaf(akr[4*u+2],kv.z, fmaf(akr[4*u+3],kv.w, sk))));
        }
        eq = __expf(fmaf(sq, 0.03125f, ab));   // (q*scale . at*scale)
        ek = __expf(fmaf(sk, SCL, ab));        // (k*scale . atk)
      }
      float tq = eq, tk = ek;
      #pragma unroll
      for (int o = 32; o > 0; o >>= 1){ tq += __shfl_xor(tq, o); tk += __shfl_xor(tk, o); }
      if (lane < 49) P[i*53 + lane] = eq/tq + ek/tk;
    }
    __syncthreads();
    if (tid < 196){
      int i = tid >> 1, dh = tid & 1;      // row i, d half
      int n = chunk*98 + i;
      float out[16];
      #pragma unroll
      for (int d = 0; d < 16; ++d) out[d] = 0.f;
      const float* pr = &P[i*53];
      #pragma unroll 7
      for (int a = 0; a < 49; ++a){
        float pv = pr[a];
        const float4* g4 = (const float4*)&sAGV[a*32 + dh*16];
        #pragma unroll
        for (int u = 0; u < 4; ++u){
          float4 gv = g4[u];
          out[4*u]   = fmaf(pv, gv.x, out[4*u]);
          out[4*u+1] = fmaf(pv, gv.y, out[4*u+1]);
          out[4*u+2] = fmaf(pv, gv.z, out[4*u+2]);
          out[4*u+3] = fmaf(pv, gv.w, out[4*u+3]);
        }
      }
      float* dst = XO + ((size_t)b*196 + n)*256 + h*32 + dh*16;
      #pragma unroll
      for (int d = 0; d < 16; ++d) dst[d] = out[d];
    }
  }
}

// ---------- fused depthwise conv: dwc(conv_x2 + qc), bias 2*dwc_b, accumulated into XO ----------
__global__ __launch_bounds__(256) void k_dwc(const float* __restrict__ Y, const float* __restrict__ CMAP,
    const float* __restrict__ dw, const float* __restrict__ db, float* __restrict__ XO){
  int b = blockIdx.x >> 3, cg = blockIdx.x & 7;
  int c0 = cg*32;
  __shared__ __align__(16) float pl[32*360];
  int tid = threadIdx.x;
  for (int t = tid; t < 32*360; t += 256) pl[t] = 0.f;
  __syncthreads();
  const float* yq = Y + (size_t)b*YSTR + QOFF;
  for (int t = tid; t < 32*196; t += 256){
    int cl = t & 31, s = t >> 5;
    int c = c0 + cl;
    int G = s*256 + c;                 // head-major flat index for conv_x2's scramble
    int hh = G / 6272;
    int rem = G - hh*6272;
    int n = rem >> 5, d = rem & 31;
    float cx2 = CMAP[b*256 + c] * yq[n*256 + hh*32 + d];   // sigmoid(cmap)*qs
    float qc  = yq[G];                                     // qc collapses to identity gather
    float v = SCL*(cx2 + qc);
    int i = s/14, j = s - i*14;
    pl[cl*360 + (i+2)*20 + j + 2] = v;
  }
  __syncthreads();
  for (int t = tid; t < 32*14; t += 256){
    int cl = t/14, r = t - cl*14;
    int c = c0 + cl;
    float w25[25];
    #pragma unroll
    for (int u = 0; u < 25; ++u) w25[u] = dw[c*25 + u];
    float acc[14];
    float b2 = 2.f*db[c];
    #pragma unroll
    for (int j = 0; j < 14; ++j) acc[j] = b2;
    conv5x5_row(&pl[cl*360], r, w25, acc);
    float* dst = XO + ((size_t)b*196 + r*14)*256 + c;
    #pragma unroll
    for (int j = 0; j < 14; ++j) dst[j*256] += acc[j];
  }
}

// ---------- final projection: out = XO @ proj_w^T + proj_b ----------
__global__ __launch_bounds__(256) void k_proj(const float* __restrict__ XO, const float* __restrict__ WT,
    const float* __restrict__ pbias, float* __restrict__ OUT){
  int bb = blockIdx.x / 7, nt = blockIdx.x % 7;
  int n0 = nt*28;
  int c = threadIdx.x;
  const float* xb = XO + ((size_t)bb*196 + n0)*256;
  float acc[28];
  #pragma unroll
  for (int r = 0; r < 28; ++r) acc[r] = 0.f;
  for (int k = 0; k < 256; k += 4){
    float w0 = WT[(k+0)*256 + c];
    float w1 = WT[(k+1)*256 + c];
    float w2 = WT[(k+2)*256 + c];
    float w3 = WT[(k+3)*256 + c];
    #pragma unroll
    for (int r = 0; r < 28; ++r){
      float4 xv = *(const float4*)(xb + r*256 + k);   // uniform address -> scalar/L1 path
      acc[r] = fmaf(xv.x, w0, fmaf(xv.y, w1, fmaf(xv.z, w2, fmaf(xv.w, w3, acc[r]))));
    }
  }
  float bv = pbias[c];
  float* dst = OUT + ((size_t)bb*196 + n0)*256 + c;
  #pragma unroll
  for (int r = 0; r < 28; ++r) dst[r*256] = acc[r] + bv;
}

extern "C" void kernel_launch(void* const* d_in, const int* in_sizes, int n_in,
                              void* d_out, int out_size, void* d_ws, size_t ws_size,
                              hipStream_t stream){
  (void)in_sizes; (void)n_in; (void)out_size; (void)ws_size;
  const float* x       = (const float*)d_in[0];
  const float* lka_w   = (const float*)d_in[3];
  const float* lka_b   = (const float*)d_in[4];
  const float* conv5_w = (const float*)d_in[5];
  const float* conv5_b = (const float*)d_in[6];
  const float* caa1_w  = (const float*)d_in[7];
  const float* caa1_b  = (const float*)d_in[8];
  const float* caa2_w  = (const float*)d_in[9];
  const float* caa2_b  = (const float*)d_in[10];
  const float* cam1_w  = (const float*)d_in[11];
  const float* cam1_b  = (const float*)d_in[12];
  const float* cam2_w  = (const float*)d_in[13];
  const float* cam2_b  = (const float*)d_in[14];
  const float* sa_w    = (const float*)d_in[15];
  const float* sa_b    = (const float*)d_in[16];
  const float* ci1_w   = (const float*)d_in[17];
  const float* ci1_b   = (const float*)d_in[18];
  const float* bn_g    = (const float*)d_in[19];
  const float* bn_b    = (const float*)d_in[20];
  const float* ci2_w   = (const float*)d_in[21];
  const float* ci2_b   = (const float*)d_in[22];
  const float* rpbt    = (const float*)d_in[23];
  const float* an_bias = (const float*)d_in[24];
  const float* na_bias = (const float*)d_in[25];
  const float* ah_bias = (const float*)d_in[26];
  const float* aw_bias = (const float*)d_in[27];
  const float* ha_bias = (const float*)d_in[28];
  const float* wa_bias = (const float*)d_in[29];
  const float* dwc_w   = (const float*)d_in[30];
  const float* dwc_b   = (const float*)d_in[31];
  const float* proj_w  = (const float*)d_in[32];
  const float* proj_b  = (const float*)d_in[33];
  float* out = (float*)d_out;
  float* ws = (float*)d_ws;

  float* Y    = ws + WS_Y;
  float* V5   = ws + WS_V5;
  float* AT   = ws + WS_AT;
  float* ATK  = ws + WS_ATK;
  float* CHG  = ws + WS_CHG;
  float* CMAP = ws + WS_CMAP;
  float* PBT  = ws + WS_PBT;
  float* AB   = ws + WS_AB;
  float* X1S  = ws + WS_X1S;
  float* AGV  = ws + WS_AGV;
  float* XO   = ws + WS_XO;
  float* WT   = ws + WS_WT;
  ushort_t* Wh = (ushort_t*)(ws + WS_CWT);

  k_pb   <<<301, 256, 0, stream>>>(an_bias, ah_bias, aw_bias, PBT);
  k_ab   <<<301, 256, 0, stream>>>(na_bias, ha_bias, wa_bias, AB);
  k_wt   <<<256, 256, 0, stream>>>(proj_w, WT);
  k_cw2  <<<6400, 256, 0, stream>>>(conv5_w, Wh);
  k_lka  <<<1024, 256, 0, stream>>>(x, lka_w, lka_b, Y);
  k_conv5<<<512, 256, 0, stream>>>(Y, Wh, conv5_b, V5);
  k_pool <<<128, 256, 0, stream>>>(Y, AT, ATK);
  k_cbam_a<<<128, 256, 0, stream>>>(V5, caa1_w, caa1_b, caa2_w, caa2_b,
                                    cam1_w, cam1_b, cam2_w, cam2_b, CHG);
  k_cbam_b<<<128, 256, 0, stream>>>(V5, CHG, sa_w, sa_b);
  k_attn <<<1024, 256, 0, stream>>>(Y, rpbt, X1S);
  k_cinter<<<128, 256, 0, stream>>>(X1S, ci1_w, ci1_b, bn_g, bn_b, ci2_w, ci2_b, CMAP);
  k_agentv<<<1024, 256, 0, stream>>>(Y, V5, AT, ATK, PBT, AGV);
  k_xo1  <<<1024, 256, 0, stream>>>(Y, AT, ATK, AB, AGV, XO);
  k_dwc  <<<1024, 256, 0, stream>>>(Y, CMAP, dwc_w, dwc_b, XO);
  k_proj <<<896, 256, 0, stream>>>(XO, WT, proj_b, out);
}

// Round 8
// 871.025 us; speedup vs baseline: 1.3490x; 1.0688x over previous
//
#include <hip/hip_runtime.h>

// Problem constants
#define NB    128
#define NC    256
#define NPOS  196
#define NHEAD 8
#define NAG   49
#define YSTR  150528      // 768*196 per-batch y floats
#define VOFF  50176       // v_raw offset inside y (256*196)
#define QOFF  100352      // q_raw offset inside y (512*196)
#define SCL   0.17677669529663687f   // 32^-0.5

// Workspace layout (floats). Total = 38,885,440 floats = 155.5 MB.
#define WS_Y    0u
#define WS_V5   19267584u
#define WS_AT   25690112u
#define WS_ATK  27295744u
#define WS_CHG  28901376u
#define WS_CMAP 28934144u
#define WS_PBT  28966912u
#define WS_AB   29043744u
#define WS_X1S  29120576u
#define WS_AGV  29153344u
#define WS_XO   30758976u
#define WS_WT   37181504u
#define WS_CWT  37247040u   // Wh: 1.6M ushort (fp16 conv5 weights, [tap][co][ci])

typedef __attribute__((ext_vector_type(8))) _Float16 half8;
typedef __attribute__((ext_vector_type(8))) short short8;
typedef __attribute__((ext_vector_type(4))) short short4v;
typedef __attribute__((ext_vector_type(4))) float f32x4;
typedef unsigned short ushort_t;
typedef unsigned int uint_t;

__device__ __forceinline__ float sigmoidf_(float x){ return 1.0f/(1.0f+__expf(-x)); }

__device__ __forceinline__ ushort_t f2h(float x){
  _Float16 h = (_Float16)x; return __builtin_bit_cast(ushort_t, h);
}
__device__ __forceinline__ float h2f(ushort_t u){
  return (float)__builtin_bit_cast(_Float16, u);
}

// bilinear upsample 7x7 -> 14x14 sample at (i,j), matching reference grid()
__device__ __forceinline__ float bilin7(const float* __restrict__ src, int i, int j){
  float pi = fmaxf(0.5f*(float)i - 0.25f, 0.f);
  int i0 = (int)pi; if (i0 > 6) i0 = 6;
  int i1 = i0 + 1;  if (i1 > 6) i1 = 6;
  float li = pi - (float)i0;
  float pj = fmaxf(0.5f*(float)j - 0.25f, 0.f);
  int j0 = (int)pj; if (j0 > 6) j0 = 6;
  int j1 = j0 + 1;  if (j1 > 6) j1 = 6;
  float lj = pj - (float)j0;
  float v00 = src[i0*7+j0], v01 = src[i0*7+j1];
  float v10 = src[i1*7+j0], v11 = src[i1*7+j1];
  float t0 = v00*(1.f-lj) + v01*lj;
  float t1 = v10*(1.f-lj) + v11*lj;
  return t0*(1.f-li) + t1*li;
}

// 5x5 conv over a zero-padded [18][20] plane, producing one 14-wide output row r.
__device__ __forceinline__ void conv5x5_row(const float* __restrict__ plane, int r,
                                            const float* __restrict__ w25, float* acc14){
  #pragma unroll
  for (int di = 0; di < 5; ++di){
    const float4* pr = (const float4*)(plane + (r+di)*20);
    float4 p0 = pr[0], p1 = pr[1], p2 = pr[2], p3 = pr[3], p4 = pr[4];
    float row[20] = {p0.x,p0.y,p0.z,p0.w, p1.x,p1.y,p1.z,p1.w, p2.x,p2.y,p2.z,p2.w,
                     p3.x,p3.y,p3.z,p3.w, p4.x,p4.y,p4.z,p4.w};
    #pragma unroll
    for (int dj = 0; dj < 5; ++dj){
      float w = w25[di*5+dj];
      #pragma unroll
      for (int j = 0; j < 14; ++j) acc14[j] = fmaf(row[j+dj], w, acc14[j]);
    }
  }
}

// ---------- prep kernels ----------
__global__ void k_pb(const float* __restrict__ an, const float* __restrict__ ah,
                     const float* __restrict__ aw, float* __restrict__ PBT){
  int t = blockIdx.x*256 + threadIdx.x;
  if (t >= NHEAD*NPOS*NAG) return;
  int a = t % NAG;
  int r = t / NAG;
  int n = r % NPOS;
  int h = r / NPOS;
  int i = n/14, j = n - (n/14)*14;
  float v = bilin7(an + ((size_t)h*NAG + a)*49, i, j);
  v += ah[((size_t)h*NAG + a)*14 + i] + aw[((size_t)h*NAG + a)*14 + j];
  PBT[t] = v;   // [h][n][a]
}

__global__ void k_ab(const float* __restrict__ na, const float* __restrict__ ha,
                     const float* __restrict__ wa, float* __restrict__ AB){
  int t = blockIdx.x*256 + threadIdx.x;
  if (t >= NHEAD*NPOS*NAG) return;
  int a = t % NAG;
  int r = t / NAG;
  int n = r % NPOS;
  int h = r / NPOS;
  int i = n/14, j = n - (n/14)*14;
  float v = bilin7(na + ((size_t)h*NAG + a)*49, i, j);
  v += ha[((size_t)h*14 + i)*NAG + a] + wa[((size_t)h*14 + j)*NAG + a];
  AB[t] = v;    // [h][n][a]
}

__global__ void k_wt(const float* __restrict__ pw, float* __restrict__ WT){
  int t = blockIdx.x*256 + threadIdx.x;
  if (t >= 65536) return;
  int k = t >> 8, c = t & 255;
  WT[t] = pw[c*256 + k];          // WT[k][c] = proj_w[c][k]
}

// conv5 weights -> fp16, layout [tap][co][ci]
__global__ void k_cw2(const float* __restrict__ cw, ushort_t* __restrict__ Wh){
  int t = blockIdx.x*256 + threadIdx.x;
  if (t >= 1638400) return;
  int ci = t & 255;
  int r  = t >> 8;
  int co = r & 255;
  int tap = r >> 8;
  Wh[t] = f2h(cw[((size_t)co*256 + ci)*25 + tap]);
}

// ---------- lka depthwise-ish conv (groups=256, 3 outputs per input channel) ----------
__global__ __launch_bounds__(256) void k_lka(const float* __restrict__ x, const float* __restrict__ lw,
                                             const float* __restrict__ lb, float* __restrict__ Y){
  int b = blockIdx.x >> 3, gb = blockIdx.x & 7;
  int g0 = gb*32;                               // input channels [g0,g0+32)
  __shared__ __align__(16) float pl[32*360];    // [ch][18*20] padded planes
  int tid = threadIdx.x;
  for (int t = tid; t < 32*360; t += 256) pl[t] = 0.f;
  __syncthreads();
  for (int t = tid; t < 32*196; t += 256){
    int gl = t & 31, s = t >> 5;
    int i = s/14, j = s - i*14;
    pl[gl*360 + (i+2)*20 + j + 2] = x[((size_t)b*196 + s)*256 + g0 + gl];
  }
  __syncthreads();
  for (int t = tid; t < 96*14; t += 256){
    int ocl = t/14, r = t - ocl*14;
    int o  = g0*3 + ocl;          // output channel; uses input channel o/3
    int gl = ocl/3;
    float w25[25];
    #pragma unroll
    for (int u = 0; u < 25; ++u) w25[u] = lw[o*25 + u];
    float acc[14];
    float bv = lb[o];
    #pragma unroll
    for (int j = 0; j < 14; ++j) acc[j] = bv;
    conv5x5_row(&pl[gl*360], r, w25, acc);
    float* dst = Y + ((size_t)b*768 + o)*196 + r*14;
    #pragma unroll
    for (int j = 0; j < 14; ++j) dst[j] = acc[j];
  }
}

// ---------- conv5 via fp16 MFMA implicit GEMM ----------
__global__ __launch_bounds__(256, 2) void k_conv5(const float* __restrict__ Y,
    const ushort_t* __restrict__ Wh, const float* __restrict__ cb, float* __restrict__ V5){
  int b = blockIdx.x >> 2, cog = blockIdx.x & 3;
  int co0 = cog*64;
  __shared__ __align__(16) ushort_t Pt[360*40];     // fp16 A: [pos][ci32 swizzled]
  __shared__ __align__(16) ushort_t Wsm[5*64*40];   // fp16 B: [tap-of-row][co][ci32 swizzled]
  __shared__ float T[32*200];                       // epilogue transpose
  int tid  = threadIdx.x;
  int lane = tid & 63, wv = tid >> 6;
  int mrow = lane & 15, quad = lane >> 4;

  // zero-fill Pt once; borders stay zero across chunks
  for (int t = tid; t < 7200; t += 256) ((uint_t*)Pt)[t] = 0;

  // per-lane A plane-row base per m-tile (unpadded base; taps add di*20+dj)
  int prow[4];
  #pragma unroll
  for (int mt = 0; mt < 4; ++mt){
    int s = wv*64 + mt*16 + mrow;
    int p0 = 0;
    if (s < 196){ int i = s/14, j = s - i*14; p0 = i*20 + j; }
    prow[mt] = p0;
  }

  f32x4 acc[4][4];
  #pragma unroll
  for (int mt = 0; mt < 4; ++mt)
    #pragma unroll
    for (int nt = 0; nt < 4; ++nt) acc[mt][nt] = (f32x4){0.f,0.f,0.f,0.f};

  const float* src = Y + (size_t)b*YSTR + VOFF;   // v_raw [ci][s]
  int wco = tid >> 2, wpart = tid & 3;            // W-staging roles

  #pragma unroll 1
  for (int cc = 0; cc < 8; ++cc){
    __syncthreads();
    // stage A: 32 ci planes -> fp16 swizzled [pos][ci]
    if (tid < 196){
      int s = tid; int i = s/14, j = s - i*14;
      int p = (i+2)*20 + (j+2);
      const float* s0 = src + (cc*32)*196 + s;
      #pragma unroll
      for (int cp = 0; cp < 16; ++cp){
        float v0 = s0[(2*cp)*196];
        float v1 = s0[(2*cp+1)*196];
        uint_t pk = (uint_t)f2h(v0) | ((uint_t)f2h(v1) << 16);
        int q = cp >> 2;
        *(uint_t*)&Pt[p*40 + (((q ^ p) & 3) << 3) + ((2*cp) & 7)] = pk;
      }
    }
    #pragma unroll 1
    for (int di = 0; di < 5; ++di){
      __syncthreads();      // Wsm free to overwrite; also fences A writes (di=0)
      // stage W: taps di*5..di*5+4, 64 co x 32 ci fp16 each
      #pragma unroll
      for (int tp = 0; tp < 5; ++tp){
        int tap = di*5 + tp;
        const short8 g = *(const short8*)(Wh + ((size_t)tap*256 + co0 + wco)*256 + cc*32 + wpart*8);
        *(short8*)&Wsm[(tp*64 + wco)*40 + (((wpart ^ wco) & 3) << 3)] = g;
      }
      __syncthreads();
      #pragma unroll
      for (int dj = 0; dj < 5; ++dj){
        half8 a[4], bb[4];
        #pragma unroll
        for (int nt = 0; nt < 4; ++nt){
          int co = nt*16 + mrow;
          bb[nt] = *(const half8*)&Wsm[(dj*64 + co)*40 + (((quad ^ co) & 3) << 3)];
        }
        #pragma unroll
        for (int mt = 0; mt < 4; ++mt){
          int p = prow[mt] + di*20 + dj;
          a[mt] = *(const half8*)&Pt[p*40 + (((quad ^ p) & 3) << 3)];
        }
        #pragma unroll
        for (int mt = 0; mt < 4; ++mt)
          #pragma unroll
          for (int nt = 0; nt < 4; ++nt)
            acc[mt][nt] = __builtin_amdgcn_mfma_f32_16x16x32_f16(a[mt], bb[nt], acc[mt][nt], 0, 0, 0);
      }
    }
  }

  // epilogue: transpose through LDS, then stores into scrambled v5
  #pragma unroll
  for (int hf = 0; hf < 2; ++hf){
    __syncthreads();
    #pragma unroll
    for (int ntl = 0; ntl < 2; ++ntl){
      int nt = hf*2 + ntl;
      int col = ntl*16 + mrow;            // co local within half (0..31)
      #pragma unroll
      for (int mt = 0; mt < 4; ++mt){
        int sbase = wv*64 + mt*16 + quad*4;
        #pragma unroll
        for (int r = 0; r < 4; ++r){
          int s = sbase + r;
          if (s < 196) T[col*200 + s] = acc[mt][nt][r];
        }
      }
    }
    __syncthreads();
    for (int t = tid; t < 6272; t += 256){
      int cl = t / 196;                   // co local 0..31
      int f = (co0 + hf*32)*196 + t;
      float val = T[t + cl*4] + cb[co0 + hf*32 + cl];
      V5[(size_t)b*50176 + (size_t)(f & 255)*196 + (f >> 8)] = val;
    }
  }
}

// ---------- agent token pooling: at = 2x2-mean of q_raw, atk = 2x2-max of k_raw ----------
__global__ __launch_bounds__(256) void k_pool(const float* __restrict__ Y, float* __restrict__ AT, float* __restrict__ ATK){
  int b = blockIdx.x; int c = threadIdx.x;
  const float* qp = Y + ((size_t)b*768 + 512 + c)*196;
  const float* kp = Y + ((size_t)b*768 + c)*196;
  for (int a = 0; a < 49; ++a){
    int p1 = a/7, p2 = a - p1*7;
    int s = p1*28 + p2*2;
    float q0 = qp[s], q1 = qp[s+1], q2 = qp[s+14], q3 = qp[s+15];
    AT[((size_t)b*49 + a)*256 + c] = 0.25f*(q0+q1+q2+q3);
    float k0 = kp[s], k1 = kp[s+1], k2 = kp[s+14], k3 = kp[s+15];
    ATK[((size_t)b*49 + a)*256 + c] = fmaxf(fmaxf(k0,k1), fmaxf(k2,k3));
  }
}

// ---------- cbam stage A: channel gate ----------
__global__ __launch_bounds__(256) void k_cbam_a(const float* __restrict__ V5,
    const float* __restrict__ caa1w, const float* __restrict__ caa1b,
    const float* __restrict__ caa2w, const float* __restrict__ caa2b,
    const float* __restrict__ cam1w, const float* __restrict__ cam1b,
    const float* __restrict__ cam2w, const float* __restrict__ cam2b,
    float* __restrict__ CHG){
  int b = blockIdx.x, c = threadIdx.x;
  __shared__ float avg[256], mx[256], t1[16], t2[16];
  const float* pp = V5 + ((size_t)b*256 + c)*196;
  float s = 0.f, m = -1e30f;
  for (int i = 0; i < 196; ++i){ float v = pp[i]; s += v; m = fmaxf(m, v); }
  avg[c] = s * (1.0f/196.0f); mx[c] = m;
  __syncthreads();
  if (c < 16){
    float a1 = caa1b[c], a2 = cam1b[c];
    #pragma unroll 4
    for (int k = 0; k < 256; ++k){
      a1 = fmaf(caa1w[(c*256 + k)*9 + 4], avg[k], a1);   // 3x3 center tap
      a2 = fmaf(cam1w[c*256 + k], mx[k], a2);            // 1x1
    }
    t1[c] = fmaxf(a1, 0.f);
    t2[c] = fmaxf(a2, 0.f);
  }
  __syncthreads();
  float y1 = caa2b[c], y2 = cam2b[c];
  #pragma unroll
  for (int k = 0; k < 16; ++k){
    y1 = fmaf(caa2w[(c*16 + k)*9 + 4], t1[k], y1);
    y2 = fmaf(cam2w[c*16 + k], t2[k], y2);
  }
  CHG[b*256 + c] = sigmoidf_(sigmoidf_(y1) + sigmoidf_(y2));
}

// ---------- cbam stage B: spatial mask (9x9 pad4 over [mean,max]) + in-place gate ----------
__global__ __launch_bounds__(256) void k_cbam_b(float* __restrict__ V5, const float* __restrict__ CHG,
    const float* __restrict__ saw, const float* __restrict__ sab){
  int b = blockIdx.x; int tid = threadIdx.x;
  __shared__ float chg[256];
  __shared__ float mp[22*22], xp[22*22];
  __shared__ float mk[196];
  chg[tid] = CHG[b*256 + tid];
  for (int t = tid; t < 484; t += 256){ mp[t] = 0.f; xp[t] = 0.f; }
  __syncthreads();
  if (tid < 196){
    int i = tid/14, j = tid - i*14;
    float s = 0.f, m = -1e30f;
    const float* vb = V5 + (size_t)b*256*196 + tid;
    for (int c = 0; c < 256; ++c){
      float v = chg[c] * vb[c*196];
      s += v; m = fmaxf(m, v);
    }
    mp[(i+4)*22 + j+4] = s*(1.f/256.f);
    xp[(i+4)*22 + j+4] = m;
  }
  __syncthreads();
  if (tid < 196){
    int i = tid/14, j = tid - i*14;
    float acc = sab[0];
    for (int di = 0; di < 9; ++di){
      #pragma unroll
      for (int dj = 0; dj < 9; ++dj){
        acc = fmaf(mp[(i+di)*22 + j+dj], saw[di*9+dj], acc);
        acc = fmaf(xp[(i+di)*22 + j+dj], saw[81 + di*9+dj], acc);
      }
    }
    mk[tid] = sigmoidf_(acc);
  }
  __syncthreads();
  if (tid < 196){
    float m = mk[tid];
    float* vb = V5 + (size_t)b*256*196 + tid;
    for (int c = 0; c < 256; ++c) vb[c*196] = chg[c]*vb[c*196]*m;
  }
}

// ---------- big NxN attention; only the per-(b,c) mean of x1 is needed downstream ----------
__global__ __launch_bounds__(256) void k_attn(const float* __restrict__ Y, const float* __restrict__ rpbt,
                                              float* __restrict__ X1S){
  int b = blockIdx.x >> 3, h = blockIdx.x & 7;
  __shared__ float rp[729];
  __shared__ float xs[196*33];
  int tid = threadIdx.x;
  for (int t = tid; t < 729; t += 256) rp[t] = rpbt[t*8 + h];
  __syncthreads();
  const float* yb = Y + (size_t)b*YSTR;
  if (tid < 196){
    int n = tid;
    float q[32];
    {
      const float4* q4 = (const float4*)(yb + QOFF + (size_t)n*256 + h*32);
      #pragma unroll
      for (int u = 0; u < 8; ++u){
        float4 v = q4[u];
        q[4*u] = v.x*SCL; q[4*u+1] = v.y*SCL; q[4*u+2] = v.z*SCL; q[4*u+3] = v.w*SCL;
      }
    }
    int ri = n/14, ci = n - ri*14;
    int bidx = (ri + 13)*27 + (ci + 13);
    float acc[32];
    #pragma unroll
    for (int d = 0; d < 32; ++d) acc[d] = 0.f;
    float l = 0.f;
    int rj = 0, cj = 0;
    for (int j = 0; j < 196; ++j){
      const float4* k4 = (const float4*)(yb + (size_t)j*256 + h*32);
      float s0 = 0.f, s1 = 0.f;
      #pragma unroll
      for (int u = 0; u < 8; u += 2){
        float4 a = k4[u], bb = k4[u+1];
        s0 = fmaf(q[4*u+0],a.x, fmaf(q[4*u+1],a.y, fmaf(q[4*u+2],a.z, fmaf(q[4*u+3],a.w, s0))));
        s1 = fmaf(q[4*u+4],bb.x, fmaf(q[4*u+5],bb.y, fmaf(q[4*u+6],bb.z, fmaf(q[4*u+7],bb.w, s1))));
      }
      float s = s0 + s1 + rp[bidx - rj*27 - cj];
      float p = __expf(s);       // logits are O(0.1): max-free softmax is safe
      l += p;
      const float4* v4 = (const float4*)(yb + VOFF + (size_t)j*256 + h*32);
      #pragma unroll
      for (int u = 0; u < 8; ++u){
        float4 vv = v4[u];
        acc[4*u]   = fmaf(p, vv.x, acc[4*u]);
        acc[4*u+1] = fmaf(p, vv.y, acc[4*u+1]);
        acc[4*u+2] = fmaf(p, vv.z, acc[4*u+2]);
        acc[4*u+3] = fmaf(p, vv.w, acc[4*u+3]);
      }
      if (++cj == 14){ cj = 0; ++rj; }
    }
    float inv = 1.f/l;
    #pragma unroll
    for (int d = 0; d < 32; ++d) xs[n*33 + d] = acc[d]*inv;
  }
  __syncthreads();
  if (tid < 32){
    float s = 0.f;
    for (int n = 0; n < 196; ++n) s += xs[n*33 + tid];
    X1S[(size_t)b*256 + h*32 + tid] = s*(1.f/196.f);   // mean over n of x1[b,:,c]
  }
}

// ---------- chan_inter on x1 mean -> sigmoid gate CMAP ----------
__global__ __launch_bounds__(256) void k_cinter(const float* __restrict__ X1S,
    const float* __restrict__ ci1w, const float* __restrict__ ci1b,
    const float* __restrict__ bng, const float* __restrict__ bnb,
    const float* __restrict__ ci2w, const float* __restrict__ ci2b, float* __restrict__ CMAP){
  int b = blockIdx.x, c = threadIdx.x;
  __shared__ float p[256], tt[16];
  p[c] = X1S[b*256 + c];
  __syncthreads();
  if (c < 16){
    float a = ci1b[c];
    #pragma unroll 4
    for (int k = 0; k < 256; ++k) a = fmaf(ci1w[(c*256+k)*25 + 12], p[k], a);  // 5x5 center
    const float invs = 0.9999950000375f;   // 1/sqrt(1+1e-5)
    tt[c] = fmaxf(fmaf(bng[c]*invs, a, bnb[c]), 0.f);
  }
  __syncthreads();
  float a = ci2b[c];
  #pragma unroll
  for (int k = 0; k < 16; ++k) a = fmaf(ci2w[(c*16+k)*25 + 12], tt[k], a);
  CMAP[b*256 + c] = sigmoidf_(a);
}

// ---------- agent_v via fp16 MFMA ----------
__global__ __launch_bounds__(256) void k_agentv(const float* __restrict__ Y, const float* __restrict__ V5,
    const float* __restrict__ AT, const float* __restrict__ ATK,
    const float* __restrict__ PBT, float* __restrict__ AGV){
  int b = blockIdx.x >> 3, h = blockIdx.x & 7;
  __shared__ __align__(16) ushort_t ST[64*232];   // exp-scores, [a][n pad 232]
  __shared__ __align__(16) ushort_t R[8704];      // staging region (17408 B)
  __shared__ float psum[4*64];
  __shared__ float inv0s[64], inv1s[64];
  int tid = threadIdx.x, wv = tid >> 6, lane = tid & 63;
  int mrow = lane & 15, quad = lane >> 4;
  const float* yb = Y + (size_t)b*YSTR;
  ushort_t* Kh = R;            // [208][32] fp16 rows (K or Q)
  ushort_t* Ah = R + 6656;     // [64][32] fp16 rows (AT or ATK)
  ushort_t* Vt = R;            // [32][232] fp16 rows (V1 or V)
  f32x4 out0[2], out1[2];

  // ---- one-time zero fills: ST cols 208..223 (cols 224-231 never read) ----
  for (int t = tid; t < 512; t += 256){      // 64 rows x 16 cols /2 per uint
    int a = t >> 3, c2 = 208 + ((t & 7) << 1);
    *(uint_t*)&ST[a*232 + c2] = 0;
  }

  #pragma unroll 1
  for (int pass = 0; pass < 2; ++pass){
    // ---- stage rows (K|Q into Kh; AT|ATK into Ah), zero pads ----
    for (int t = tid; t < 192; t += 256) ((uint_t*)Kh)[3136 + t] = 0;   // rows 196-207
    for (int t = tid; t < 240; t += 256) ((uint_t*)Ah)[784 + t] = 0;    // rows 49-63
    {
      const float* rsrc = yb + (pass ? QOFF : 0) + h*32;
      for (int t = tid; t < 3136; t += 256){
        int n = t >> 4, dp = (t & 15) << 1;
        const float2 v = *(const float2*)(rsrc + (size_t)n*256 + dp);
        ((uint_t*)Kh)[n*16 + (dp >> 1)] = (uint_t)f2h(v.x) | ((uint_t)f2h(v.y) << 16);
      }
      const float* asrc = (pass ? ATK : AT) + (size_t)b*49*256 + h*32;
      for (int t = tid; t < 784; t += 256){
        int a = t >> 4, dp = (t & 15) << 1;
        const float2 v = *(const float2*)(asrc + (size_t)a*256 + dp);
        ((uint_t*)Ah)[a*16 + (dp >> 1)] = (uint_t)f2h(v.x) | ((uint_t)f2h(v.y) << 16);
      }
    }
    __syncthreads();
    // ---- logits: ntile = wv; 13 mtiles; exp(+pb) -> ST[a][n] ----
    {
      float lscl = pass ? 0.03125f : SCL;
      int ag = wv*16 + mrow;                 // agent (C col)
      half8 bfr = *(const half8*)&Ah[ag*32 + quad*8];
      #pragma unroll 1
      for (int mt = 0; mt < 13; ++mt){
        half8 afr = *(const half8*)&Kh[(mt*16 + mrow)*32 + quad*8];
        f32x4 c = (f32x4){0.f,0.f,0.f,0.f};
        c = __builtin_amdgcn_mfma_f32_16x16x32_f16(afr, bfr, c, 0, 0, 0);
        int n0 = mt*16 + quad*4;
        short4v pk;
        #pragma unroll
        for (int r = 0; r < 4; ++r){
          int n = n0 + r;
          float pb = PBT[((size_t)h*196 + n)*49 + ag];
          float e = (n < 196) ? __expf(fmaf(c[r], lscl, pb)) : 0.f;
          pk[r] = (short)f2h(e);
        }
        *(short4v*)&ST[ag*232 + n0] = pk;
      }
    }
    __syncthreads();
    // ---- denominators + stage V ----
    {
      int a = tid >> 2, q = tid & 3;
      float s = 0.f;
      #pragma unroll
      for (int u = 0; u < 7; ++u){
        short8 v8 = *(const short8*)&ST[a*232 + q*56 + u*8];
        #pragma unroll
        for (int e = 0; e < 8; ++e) s += h2f((ushort_t)v8[e]);
      }
      psum[q*64 + a] = s;
    }
    if (pass == 0){
      const float* vsrc = V5 + (size_t)b*50176 + h*32*196;   // [d][196]
      for (int t = tid; t < 3136; t += 256){
        int d = t / 98, np = t - (t/98)*98;
        const float2 v = *(const float2*)(vsrc + (size_t)d*196 + 2*np);
        *(uint_t*)&Vt[d*232 + 2*np] = (uint_t)f2h(v.x) | ((uint_t)f2h(v.y) << 16);
      }
    } else {
      const float* vsrc = yb + VOFF + h*32;                  // [n][256]
      for (int t = tid; t < 3136; t += 256){
        int d = t / 98, np = t - (t/98)*98;
        float v0 = vsrc[(size_t)(2*np)*256 + d];
        float v1 = vsrc[(size_t)(2*np+1)*256 + d];
        *(uint_t*)&Vt[d*232 + 2*np] = (uint_t)f2h(v0) | ((uint_t)f2h(v1) << 16);
      }
    }
    for (int t = tid; t < 448; t += 256){    // zero V cols 196..223
      int d = t / 14, c2 = 196 + 2*(t - (t/14)*14);
      *(uint_t*)&Vt[d*232 + c2] = 0;
    }
    __syncthreads();
    // ---- PV: mtile = wv (a rows); ntile 0..1 (d cols); 7 k-steps ----
    {
      f32x4* outp = pass ? out1 : out0;
      #pragma unroll
      for (int nt = 0; nt < 2; ++nt){
        f32x4 c = (f32x4){0.f,0.f,0.f,0.f};
        #pragma unroll
        for (int ks = 0; ks < 7; ++ks){
          half8 afr = *(const half8*)&ST[(wv*16 + mrow)*232 + ks*32 + quad*8];
          half8 bfr = *(const half8*)&Vt[(nt*16 + mrow)*232 + ks*32 + quad*8];
          c = __builtin_amdgcn_mfma_f32_16x16x32_f16(afr, bfr, c, 0, 0, 0);
        }
        outp[nt] = c;
      }
      if (tid < 64){
        float s = psum[tid] + psum[64+tid] + psum[128+tid] + psum[192+tid];
        float* invp = pass ? inv1s : inv0s;
        invp[tid] = 1.f / s;
      }
    }
    __syncthreads();   // ST/Vt free for next pass; inv visible
  }
  // ---- epilogue: combine + scatter ----
  #pragma unroll
  for (int nt = 0; nt < 2; ++nt){
    int d = nt*16 + mrow;
    #pragma unroll
    for (int r = 0; r < 4; ++r){
      int a = wv*16 + quad*4 + r;
      if (a < 49)
        AGV[(((size_t)(b*8 + h)*49) + a)*32 + d] = out0[nt][r]*inv0s[a] + out1[nt][r]*inv1s[a];
    }
  }
}

// ---------- xo1 via fp16 MFMA ----------
// Per (b,h), pass p in {q,k}: S[196][49] = rows . agents^T (one 16x16x32 MFMA
// per tile, K=32 exact); e = exp(S*lscl + AB) -> ST[n][a] fp16 (stride 72);
// row sums -> invs[n]; out[196][32] += invs[n] * (ST . AGV^T) (K=64, 2 steps).
// 1/s[n] is per-M-row so it factors out of the PV GEMM. AGV^T staged once.
__global__ __launch_bounds__(256) void k_xo1(const float* __restrict__ Y,
    const float* __restrict__ AT, const float* __restrict__ ATK,
    const float* __restrict__ AB, const float* __restrict__ AGV, float* __restrict__ XO){
  int b = blockIdx.x >> 3, h = blockIdx.x & 7;
  __shared__ __align__(16) ushort_t ST[208*72];   // exp-scores [n][a pad 72]
  __shared__ __align__(16) ushort_t Kh[208*32];   // Q or K rows fp16
  __shared__ __align__(16) ushort_t Ah[64*32];    // AT or ATK rows fp16
  __shared__ __align__(16) ushort_t AGVt[32*64];  // AGV^T [d][a]
  __shared__ float invs[208];
  int tid = threadIdx.x, wv = tid >> 6, lane = tid & 63;
  int mrow = lane & 15, quad = lane >> 4;
  const float* yb = Y + (size_t)b*YSTR;
  f32x4 acc[4][2];
  #pragma unroll
  for (int i = 0; i < 4; ++i){
    acc[i][0] = (f32x4){0.f,0.f,0.f,0.f};
    acc[i][1] = (f32x4){0.f,0.f,0.f,0.f};
  }

  // one-time: zero ST cols 48..63 (a-pad = K-dim of PV; col 48 rewritten by
  // logits each pass), stage AGV^T with a-pad zeros
  for (int t = tid; t < 1664; t += 256){
    int rw = t >> 3, c2 = 48 + ((t & 7) << 1);
    *(uint_t*)&ST[rw*72 + c2] = 0;
  }
  {
    const float* agvb = AGV + (size_t)(b*8 + h)*49*32;
    for (int t = tid; t < 2048; t += 256){
      int d = t >> 6, a = t & 63;
      AGVt[d*64 + a] = (a < 49) ? f2h(agvb[a*32 + d]) : (ushort_t)0;
    }
  }

  #pragma unroll 1
  for (int pass = 0; pass < 2; ++pass){
    // ---- stage rows: pass0 = Q rows + AT agents; pass1 = K rows + ATK ----
    {
      const float* rsrc = yb + (pass ? 0 : QOFF) + h*32;
      for (int t = tid; t < 3136; t += 256){
        int n = t >> 4, dp = (t & 15) << 1;
        const float2 v = *(const float2*)(rsrc + (size_t)n*256 + dp);
        ((uint_t*)Kh)[n*16 + (dp >> 1)] = (uint_t)f2h(v.x) | ((uint_t)f2h(v.y) << 16);
      }
      const float* asrc = (pass ? ATK : AT) + (size_t)b*49*256 + h*32;
      for (int t = tid; t < 784; t += 256){
        int a = t >> 4, dp = (t & 15) << 1;
        const float2 v = *(const float2*)(asrc + (size_t)a*256 + dp);
        ((uint_t*)Ah)[a*16 + (dp >> 1)] = (uint_t)f2h(v.x) | ((uint_t)f2h(v.y) << 16);
      }
    }
    __syncthreads();
    // ---- logits: ag = wv*16+mrow (C col); 13 mtiles; e -> ST[n][ag] ----
    {
      float lscl = pass ? SCL : 0.03125f;
      int ag = wv*16 + mrow;
      half8 bfr = *(const half8*)&Ah[ag*32 + quad*8];
      #pragma unroll 1
      for (int mt = 0; mt < 13; ++mt){
        half8 afr = *(const half8*)&Kh[(mt*16 + mrow)*32 + quad*8];
        f32x4 c = (f32x4){0.f,0.f,0.f,0.f};
        c = __builtin_amdgcn_mfma_f32_16x16x32_f16(afr, bfr, c, 0, 0, 0);
        #pragma unroll
        for (int r = 0; r < 4; ++r){
          int n = mt*16 + quad*4 + r;
          if (n < 196 && ag < 49){
            float e = __expf(fmaf(c[r], lscl, AB[((size_t)h*196 + n)*49 + ag]));
            ST[n*72 + ag] = f2h(e);
          }
        }
      }
    }
    __syncthreads();
    // ---- row sums over agents -> invs[n] (cols 49..55 are zeros) ----
    if (tid < 196){
      float s = 0.f;
      #pragma unroll
      for (int u = 0; u < 7; ++u){
        short8 v8 = *(const short8*)&ST[tid*72 + u*8];
        #pragma unroll
        for (int e = 0; e < 8; ++e) s += h2f((ushort_t)v8[e]);
      }
      invs[tid] = 1.f / s;
    }
    __syncthreads();
    // ---- PV: wave strides mtiles; 2 ntiles x 2 ksteps; acc += c*invs[n] ----
    {
      int i = 0;
      #pragma unroll 1
      for (int mt = wv; mt < 13; mt += 4, ++i){
        #pragma unroll
        for (int nt = 0; nt < 2; ++nt){
          f32x4 c = (f32x4){0.f,0.f,0.f,0.f};
          #pragma unroll
          for (int ks = 0; ks < 2; ++ks){
            half8 afr = *(const half8*)&ST[(mt*16 + mrow)*72 + ks*32 + quad*8];
            half8 bfr = *(const half8*)&AGVt[(nt*16 + mrow)*64 + ks*32 + quad*8];
            c = __builtin_amdgcn_mfma_f32_16x16x32_f16(afr, bfr, c, 0, 0, 0);
          }
          #pragma unroll
          for (int r = 0; r < 4; ++r){
            int n = mt*16 + quad*4 + r;
            if (n < 196) acc[i][nt][r] = fmaf(c[r], invs[n], acc[i][nt][r]);
          }
        }
      }
    }
    __syncthreads();   // ST/Kh/Ah/invs free for next pass
  }
  // ---- store XO ----
  {
    int i = 0;
    #pragma unroll 1
    for (int mt = wv; mt < 13; mt += 4, ++i){
      #pragma unroll
      for (int nt = 0; nt < 2; ++nt){
        #pragma unroll
        for (int r = 0; r < 4; ++r){
          int n = mt*16 + quad*4 + r;
          if (n < 196)
            XO[((size_t)b*196 + n)*256 + h*32 + nt*16 + mrow] = acc[i][nt][r];
        }
      }
    }
  }
}

// ---------- fused depthwise conv: dwc(conv_x2 + qc), bias 2*dwc_b, accumulated into XO ----------
__global__ __launch_bounds__(256) void k_dwc(const float* __restrict__ Y, const float* __restrict__ CMAP,
    const float* __restrict__ dw, const float* __restrict__ db, float* __restrict__ XO){
  int b = blockIdx.x >> 3, cg = blockIdx.x & 7;
  int c0 = cg*32;
  __shared__ __align__(16) float pl[32*360];
  int tid = threadIdx.x;
  for (int t = tid; t < 32*360; t += 256) pl[t] = 0.f;
  __syncthreads();
  const float* yq = Y + (size_t)b*YSTR + QOFF;
  for (int t = tid; t < 32*196; t += 256){
    int cl = t & 31, s = t >> 5;
    int c = c0 + cl;
    int G = s*256 + c;                 // head-major flat index for conv_x2's scramble
    int hh = G / 6272;
    int rem = G - hh*6272;
    int n = rem >> 5, d = rem & 31;
    float cx2 = CMAP[b*256 + c] * yq[n*256 + hh*32 + d];   // sigmoid(cmap)*qs
    float qc  = yq[G];                                     // qc collapses to identity gather
    float v = SCL*(cx2 + qc);
    int i = s/14, j = s - i*14;
    pl[cl*360 + (i+2)*20 + j + 2] = v;
  }
  __syncthreads();
  for (int t = tid; t < 32*14; t += 256){
    int cl = t/14, r = t - cl*14;
    int c = c0 + cl;
    float w25[25];
    #pragma unroll
    for (int u = 0; u < 25; ++u) w25[u] = dw[c*25 + u];
    float acc[14];
    float b2 = 2.f*db[c];
    #pragma unroll
    for (int j = 0; j < 14; ++j) acc[j] = b2;
    conv5x5_row(&pl[cl*360], r, w25, acc);
    float* dst = XO + ((size_t)b*196 + r*14)*256 + c;
    #pragma unroll
    for (int j = 0; j < 14; ++j) dst[j*256] += acc[j];
  }
}

// ---------- final projection: out = XO @ proj_w^T + proj_b ----------
__global__ __launch_bounds__(256) void k_proj(const float* __restrict__ XO, const float* __restrict__ WT,
    const float* __restrict__ pbias, float* __restrict__ OUT){
  int bb = blockIdx.x / 7, nt = blockIdx.x % 7;
  int n0 = nt*28;
  int c = threadIdx.x;
  const float* xb = XO + ((size_t)bb*196 + n0)*256;
  float acc[28];
  #pragma unroll
  for (int r = 0; r < 28; ++r) acc[r] = 0.f;
  for (int k = 0; k < 256; k += 4){
    float w0 = WT[(k+0)*256 + c];
    float w1 = WT[(k+1)*256 + c];
    float w2 = WT[(k+2)*256 + c];
    float w3 = WT[(k+3)*256 + c];
    #pragma unroll
    for (int r = 0; r < 28; ++r){
      float4 xv = *(const float4*)(xb + r*256 + k);   // uniform address -> scalar/L1 path
      acc[r] = fmaf(xv.x, w0, fmaf(xv.y, w1, fmaf(xv.z, w2, fmaf(xv.w, w3, acc[r]))));
    }
  }
  float bv = pbias[c];
  float* dst = OUT + ((size_t)bb*196 + n0)*256 + c;
  #pragma unroll
  for (int r = 0; r < 28; ++r) dst[r*256] = acc[r] + bv;
}

extern "C" void kernel_launch(void* const* d_in, const int* in_sizes, int n_in,
                              void* d_out, int out_size, void* d_ws, size_t ws_size,
                              hipStream_t stream){
  (void)in_sizes; (void)n_in; (void)out_size; (void)ws_size;
  const float* x       = (const float*)d_in[0];
  const float* lka_w   = (const float*)d_in[3];
  const float* lka_b   = (const float*)d_in[4];
  const float* conv5_w = (const float*)d_in[5];
  const float* conv5_b = (const float*)d_in[6];
  const float* caa1_w  = (const float*)d_in[7];
  const float* caa1_b  = (const float*)d_in[8];
  const float* caa2_w  = (const float*)d_in[9];
  const float* caa2_b  = (const float*)d_in[10];
  const float* cam1_w  = (const float*)d_in[11];
  const float* cam1_b  = (const float*)d_in[12];
  const float* cam2_w  = (const float*)d_in[13];
  const float* cam2_b  = (const float*)d_in[14];
  const float* sa_w    = (const float*)d_in[15];
  const float* sa_b    = (const float*)d_in[16];
  const float* ci1_w   = (const float*)d_in[17];
  const float* ci1_b   = (const float*)d_in[18];
  const float* bn_g    = (const float*)d_in[19];
  const float* bn_b    = (const float*)d_in[20];
  const float* ci2_w   = (const float*)d_in[21];
  const float* ci2_b   = (const float*)d_in[22];
  const float* rpbt    = (const float*)d_in[23];
  const float* an_bias = (const float*)d_in[24];
  const float* na_bias = (const float*)d_in[25];
  const float* ah_bias = (const float*)d_in[26];
  const float* aw_bias = (const float*)d_in[27];
  const float* ha_bias = (const float*)d_in[28];
  const float* wa_bias = (const float*)d_in[29];
  const float* dwc_w   = (const float*)d_in[30];
  const float* dwc_b   = (const float*)d_in[31];
  const float* proj_w  = (const float*)d_in[32];
  const float* proj_b  = (const float*)d_in[33];
  float* out = (float*)d_out;
  float* ws = (float*)d_ws;

  float* Y    = ws + WS_Y;
  float* V5   = ws + WS_V5;
  float* AT   = ws + WS_AT;
  float* ATK  = ws + WS_ATK;
  float* CHG  = ws + WS_CHG;
  float* CMAP = ws + WS_CMAP;
  float* PBT  = ws + WS_PBT;
  float* AB   = ws + WS_AB;
  float* X1S  = ws + WS_X1S;
  float* AGV  = ws + WS_AGV;
  float* XO   = ws + WS_XO;
  float* WT   = ws + WS_WT;
  ushort_t* Wh = (ushort_t*)(ws + WS_CWT);

  k_pb   <<<301, 256, 0, stream>>>(an_bias, ah_bias, aw_bias, PBT);
  k_ab   <<<301, 256, 0, stream>>>(na_bias, ha_bias, wa_bias, AB);
  k_wt   <<<256, 256, 0, stream>>>(proj_w, WT);
  k_cw2  <<<6400, 256, 0, stream>>>(conv5_w, Wh);
  k_lka  <<<1024, 256, 0, stream>>>(x, lka_w, lka_b, Y);
  k_conv5<<<512, 256, 0, stream>>>(Y, Wh, conv5_b, V5);
  k_pool <<<128, 256, 0, stream>>>(Y, AT, ATK);
  k_cbam_a<<<128, 256, 0, stream>>>(V5, caa1_w, caa1_b, caa2_w, caa2_b,
                                    cam1_w, cam1_b, cam2_w, cam2_b, CHG);
  k_cbam_b<<<128, 256, 0, stream>>>(V5, CHG, sa_w, sa_b);
  k_attn <<<1024, 256, 0, stream>>>(Y, rpbt, X1S);
  k_cinter<<<128, 256, 0, stream>>>(X1S, ci1_w, ci1_b, bn_g, bn_b, ci2_w, ci2_b, CMAP);
  k_agentv<<<1024, 256, 0, stream>>>(Y, V5, AT, ATK, PBT, AGV);
  k_xo1  <<<1024, 256, 0, stream>>>(Y, AT, ATK, AB, AGV, XO);
  k_dwc  <<<1024, 256, 0, stream>>>(Y, CMAP, dwc_w, dwc_b, XO);
  k_proj <<<896, 256, 0, stream>>>(XO, WT, proj_b, out);
}